// Round 6
// baseline (1003.271 us; speedup 1.0000x reference)
//
#include <hip/hip_runtime.h>
#include <stdint.h>
#include <stddef.h>

// SwinV2-B stage-3 window attention, MI355X bf16-MFMA pipeline.
// Round 6: single-barrier phases in the 8-wave 256x256 zigzag pipeline
// (reads of phase p+1 overlap other waves' MFMA of phase p).
// Big ws layout (ws_size >= 543,178,752 B):
//   [0)            QKV bf16 [131072][1536]
//   [402653184)    XB  bf16 [131072][512]
//   [536870912)    CMB f32 [16w][16h][64][64]
//   [541065216)    SIG f32 [225][16] (pad 16K)
//   [541081600)    WQB bf16 [1536][512]
//   [542654464)    WPB bf16 [512][512]

typedef __attribute__((ext_vector_type(8))) short bf16x8;
typedef __attribute__((ext_vector_type(4))) float f32x4;
typedef __attribute__((ext_vector_type(4))) unsigned short us4;
typedef __attribute__((ext_vector_type(8))) unsigned short us8;
typedef unsigned short u16;
typedef unsigned int u32;

#define FENCE() asm volatile("" ::: "memory")
#define WAITV4() asm volatile("s_waitcnt vmcnt(4)" ::: "memory")
#define WAITV0() asm volatile("s_waitcnt vmcnt(0)" ::: "memory")
#define WAITL0() asm volatile("s_waitcnt lgkmcnt(0)" ::: "memory")

__device__ __forceinline__ u16 f2bf(float f) {
  union { __bf16 b; u16 u; } cv;
  cv.b = (__bf16)f;            // hardware RNE convert on gfx950
  return cv.u;
}
__device__ __forceinline__ float bf2f(u16 s) {
  return __uint_as_float(((u32)s) << 16);
}
__device__ __forceinline__ void gl_lds16(const void* g, void* l) {
  __builtin_amdgcn_global_load_lds(
      (const __attribute__((address_space(1))) u32*)g,
      (__attribute__((address_space(3))) u32*)l, 16, 0, 0);
}
__device__ __forceinline__ f32x4 mfma16(bf16x8 a, bf16x8 b, f32x4 c) {
  return __builtin_amdgcn_mfma_f32_16x16x32_bf16(a, b, c, 0, 0, 0);
}
__device__ __forceinline__ bf16x8 ldswz(const u16* p, int ks) {
  return *(const bf16x8*)((const u16*)((uintptr_t)p ^ (uintptr_t)(ks << 6)));
}

// ---------------- prep kernels ----------------

__global__ void conv_w_kernel(const float* __restrict__ QW, const float* __restrict__ PW,
                              u16* __restrict__ WQB, u16* __restrict__ WPB) {
  int idx = blockIdx.x * 256 + threadIdx.x;   // 262144 float4 chunks total
  const int NQ = 1536 * 512 / 4;              // 196608
  float4 v; u16* dst;
  if (idx < NQ) { v = ((const float4*)QW)[idx]; dst = WQB + (size_t)idx * 4; }
  else { int k = idx - NQ; v = ((const float4*)PW)[k]; dst = WPB + (size_t)k * 4; }
  us4 u; u.x = f2bf(v.x); u.y = f2bf(v.y); u.z = f2bf(v.z); u.w = f2bf(v.w);
  *(us4*)dst = u;
}

__global__ void xconv_kernel(const float* __restrict__ X, u16* __restrict__ XB) {
  size_t idx = (size_t)blockIdx.x * 256 + threadIdx.x;   // 8,388,608 threads, 8 f32 each
  float4 a = ((const float4*)X)[idx * 2];
  float4 b = ((const float4*)X)[idx * 2 + 1];
  us8 o;
  o[0] = f2bf(a.x); o[1] = f2bf(a.y); o[2] = f2bf(a.z); o[3] = f2bf(a.w);
  o[4] = f2bf(b.x); o[5] = f2bf(b.y); o[6] = f2bf(b.z); o[7] = f2bf(b.w);
  *(us8*)&XB[idx * 8] = o;
}

__global__ void sig16_kernel(const float* __restrict__ CT, const float* __restrict__ W1,
                             const float* __restrict__ B1, const float* __restrict__ W2,
                             float* __restrict__ SIG) {
  int i = blockIdx.x;            // 0..224
  int tid = threadIdx.x;         // 256
  float c0 = CT[i * 2 + 0], c1 = CT[i * 2 + 1];
  float a[16];
  #pragma unroll
  for (int hh = 0; hh < 16; ++hh) a[hh] = 0.f;
  #pragma unroll
  for (int jj = 0; jj < 2; ++jj) {
    int j = tid + jj * 256;
    float h = fmaxf(c0 * W1[j * 2 + 0] + c1 * W1[j * 2 + 1] + B1[j], 0.f);
    #pragma unroll
    for (int hh = 0; hh < 16; ++hh) a[hh] += h * W2[hh * 512 + j];
  }
  __shared__ float red[4][16];
  #pragma unroll
  for (int hh = 0; hh < 16; ++hh) {
    float v = a[hh];
    for (int m = 1; m < 64; m <<= 1) v += __shfl_xor(v, m);
    if ((tid & 63) == 0) red[tid >> 6][hh] = v;
  }
  __syncthreads();
  if (tid < 16) {
    float v = red[0][tid] + red[1][tid] + red[2][tid] + red[3][tid];
    SIG[i * 16 + tid] = 16.f / (1.f + __expf(-v));
  }
}

__global__ void cmb_kernel(const float* __restrict__ SIG, const float* __restrict__ MASK,
                           const int* __restrict__ RPI, float* __restrict__ CMB) {
  int b = blockIdx.x;            // (w,h) = 256 blocks
  int w = b >> 4, h = b & 15;
  int tid = threadIdx.x;
  const float* mrow = &MASK[(size_t)w * 4096];
  float* crow = &CMB[(size_t)b * 4096];
  #pragma unroll
  for (int it = 0; it < 16; ++it) {
    int nm = it * 256 + tid;
    crow[nm] = SIG[RPI[nm] * 16 + h] + mrow[nm];
  }
}

// ============ shared 256x256/8-wave zigzag pipeline (macro body) ============
// Phase = { reads | stage issue | (vmcnt) } -> s_barrier -> lgkmcnt(0) -> MFMA.
// ONE barrier per phase: safety holds because every staged region is >=1 full
// barrier past its last reader's lgkmcnt drain (see round-6 analysis).
// Stages: P0->B1(t+1), P1->A1(t+1), P2->A0(t+2), P3->B0(t+2)+vmcnt(4).
// vmcnt(4) at P3 retires exactly all 8 older instructions = tile t+1 complete.

#define MFMA_QUAD(MB, NB, B0, B1)                                          \
  FENCE(); __builtin_amdgcn_s_barrier(); FENCE();                          \
  WAITL0(); __builtin_amdgcn_sched_barrier(0);                             \
  __builtin_amdgcn_s_setprio(1);                                           \
  _Pragma("unroll")                                                        \
  for (int m = 0; m < 4; ++m)                                              \
    _Pragma("unroll")                                                      \
    for (int n = 0; n < 2; ++n) {                                          \
      acc[(MB) + m][(NB) + n] = mfma16(af0[m], B0[n], acc[(MB) + m][(NB) + n]); \
      acc[(MB) + m][(NB) + n] = mfma16(af1[m], B1[n], acc[(MB) + m][(NB) + n]); \
    }                                                                      \
  __builtin_amdgcn_s_setprio(0);

#define GEMM8_KLOOP()                                                      \
  for (int t = 0; t < 8; ++t) {                                            \
    const int buf = (t & 1) * 32768;                                       \
    /* P0 */                                                               \
    _Pragma("unroll")                                                      \
    for (int m = 0; m < 4; ++m) {                                          \
      const u16* pA = &S[buf + (wm * 64 + m * 16 + fr) * 64 + fsw];        \
      af0[m] = ldswz(pA, 0); af1[m] = ldswz(pA, 1);                        \
    }                                                                      \
    _Pragma("unroll")                                                      \
    for (int n = 0; n < 2; ++n) {                                          \
      const u16* pB = &S[buf + 16384 + (wn * 32 + n * 16 + fr) * 64 + fsw];\
      b00[n] = ldswz(pB, 0); b01[n] = ldswz(pB, 1);                        \
    }                                                                      \
    if (t < 7) stageB(t + 1, 1);                                           \
    MFMA_QUAD(0, 0, b00, b01)                                              \
    /* P1 */                                                               \
    _Pragma("unroll")                                                      \
    for (int n = 0; n < 2; ++n) {                                          \
      const u16* pB = &S[buf + 16384 + (128 + wn * 32 + n * 16 + fr) * 64 + fsw]; \
      b10[n] = ldswz(pB, 0); b11[n] = ldswz(pB, 1);                        \
    }                                                                      \
    if (t < 7) stageA(t + 1, 1);                                           \
    MFMA_QUAD(0, 2, b10, b11)                                              \
    /* P2 */                                                               \
    _Pragma("unroll")                                                      \
    for (int m = 0; m < 4; ++m) {                                          \
      const u16* pA = &S[buf + (128 + wm * 64 + m * 16 + fr) * 64 + fsw];  \
      af0[m] = ldswz(pA, 0); af1[m] = ldswz(pA, 1);                        \
    }                                                                      \
    if (t < 6) stageA(t + 2, 0);                                           \
    MFMA_QUAD(4, 2, b10, b11)                                              \
    /* P3 */                                                               \
    if (t < 6) { stageB(t + 2, 0); WAITV4(); }                             \
    else if (t == 6) { WAITV0(); }                                         \
    MFMA_QUAD(4, 0, b00, b01)                                              \
  }

// ---------------- qkv GEMM: XB bf16 [131072,512] @ WQB^T -> bf16 [131072,1536] ----

__global__ __launch_bounds__(512, 1) void qkv_gemm8(
    const u16* __restrict__ XB, const u16* __restrict__ WB,
    const float* __restrict__ QB, const float* __restrict__ VB,
    u16* __restrict__ QKV) {
  __shared__ u16 S[65536];  // [buf:2][ A[256][64] | B[256][64] ]  131072 B
  const int tid = threadIdx.x, lane = tid & 63, w = tid >> 6;
  int bid = blockIdx.x;                           // 3072 = 512m x 6n
  int swz = (bid & 7) * 384 + (bid >> 3);         // bijective XCD swizzle
  const int mt = swz / 6, nt = swz - mt * 6;
  const long m0 = (long)mt * 256, n0 = (long)nt * 256;
  const int wm = w >> 2, wn = w & 3;
  const int fr = lane & 15, lg = lane >> 4;
  const int fsw = (lg ^ (lane & 7)) << 3;
  const f32x4 zf = {0.f, 0.f, 0.f, 0.f};

  f32x4 acc[8][4];
  #pragma unroll
  for (int mi = 0; mi < 8; ++mi)
    #pragma unroll
    for (int ni = 0; ni < 4; ++ni) acc[mi][ni] = zf;

  auto stageA = [&](int kt, int h) {
    int dst = (kt & 1) * 32768 + h * 8192;
    #pragma unroll
    for (int i = 0; i < 2; ++i) {
      int ch = i * 512 + tid;
      int row = ch >> 3, kcs = (ch & 7) ^ (row & 7);
      gl_lds16(&XB[(size_t)(m0 + h * 128 + row) * 512 + kt * 64 + kcs * 8],
               &S[dst + (i * 512 + w * 64) * 8]);
    }
  };
  auto stageB = [&](int kt, int h) {
    int dst = (kt & 1) * 32768 + 16384 + h * 8192;
    #pragma unroll
    for (int i = 0; i < 2; ++i) {
      int ch = i * 512 + tid;
      int row = ch >> 3, kcs = (ch & 7) ^ (row & 7);
      gl_lds16(&WB[(size_t)(n0 + h * 128 + row) * 512 + kt * 64 + kcs * 8],
               &S[dst + (i * 512 + w * 64) * 8]);
    }
  };

  bf16x8 af0[4], af1[4], b00[2], b01[2], b10[2], b11[2];

  stageA(0, 0); stageB(0, 0); stageB(0, 1); stageA(0, 1);
  stageA(1, 0); stageB(1, 0);
  WAITV4();
  FENCE(); __builtin_amdgcn_s_barrier(); FENCE();

  GEMM8_KLOOP()

  #pragma unroll
  for (int ni = 0; ni < 4; ++ni) {
    const long c = n0 + (ni >> 1) * 128 + wn * 32 + (ni & 1) * 16 + fr;
    float bias = (c < 512) ? QB[c] : (c < 1024 ? 0.f : VB[c - 1024]);
    #pragma unroll
    for (int mi = 0; mi < 8; ++mi)
      #pragma unroll
      for (int r = 0; r < 4; ++r) {
        long row = m0 + (mi >> 2) * 128 + wm * 64 + (mi & 3) * 16 + lg * 4 + r;
        QKV[row * 1536 + c] = f2bf(acc[mi][ni][r] + bias);
      }
  }
}

// ---------------- proj GEMM: QKV q-cols bf16 [131072,512](lda=1536) @ WPB^T + b -> f32 ----

__global__ __launch_bounds__(512, 1) void proj_gemm8(
    const u16* __restrict__ A, const u16* __restrict__ WB,
    const float* __restrict__ PB, float* __restrict__ OUT) {
  __shared__ u16 S[65536];
  const int tid = threadIdx.x, lane = tid & 63, w = tid >> 6;
  int bid = blockIdx.x;                           // 1024 = 512m x 2n
  int swz = (bid & 7) * 128 + (bid >> 3);
  const int mt = swz >> 1, nt = swz & 1;
  const long m0 = (long)mt * 256, n0 = (long)nt * 256;
  const int wm = w >> 2, wn = w & 3;
  const int fr = lane & 15, lg = lane >> 4;
  const int fsw = (lg ^ (lane & 7)) << 3;
  const f32x4 zf = {0.f, 0.f, 0.f, 0.f};

  f32x4 acc[8][4];
  #pragma unroll
  for (int mi = 0; mi < 8; ++mi)
    #pragma unroll
    for (int ni = 0; ni < 4; ++ni) acc[mi][ni] = zf;

  auto stageA = [&](int kt, int h) {
    int dst = (kt & 1) * 32768 + h * 8192;
    #pragma unroll
    for (int i = 0; i < 2; ++i) {
      int ch = i * 512 + tid;
      int row = ch >> 3, kcs = (ch & 7) ^ (row & 7);
      gl_lds16(&A[(size_t)(m0 + h * 128 + row) * 1536 + kt * 64 + kcs * 8],
               &S[dst + (i * 512 + w * 64) * 8]);
    }
  };
  auto stageB = [&](int kt, int h) {
    int dst = (kt & 1) * 32768 + 16384 + h * 8192;
    #pragma unroll
    for (int i = 0; i < 2; ++i) {
      int ch = i * 512 + tid;
      int row = ch >> 3, kcs = (ch & 7) ^ (row & 7);
      gl_lds16(&WB[(size_t)(n0 + h * 128 + row) * 512 + kt * 64 + kcs * 8],
               &S[dst + (i * 512 + w * 64) * 8]);
    }
  };

  bf16x8 af0[4], af1[4], b00[2], b01[2], b10[2], b11[2];

  stageA(0, 0); stageB(0, 0); stageB(0, 1); stageA(0, 1);
  stageA(1, 0); stageB(1, 0);
  WAITV4();
  FENCE(); __builtin_amdgcn_s_barrier(); FENCE();

  GEMM8_KLOOP()

  #pragma unroll
  for (int ni = 0; ni < 4; ++ni) {
    const long c = n0 + (ni >> 1) * 128 + wn * 32 + (ni & 1) * 16 + fr;
    float bias = PB[c];
    #pragma unroll
    for (int mi = 0; mi < 8; ++mi)
      #pragma unroll
      for (int r = 0; r < 4; ++r) {
        long row = m0 + (mi >> 2) * 128 + wm * 64 + (mi & 3) * 16 + lg * 4 + r;
        OUT[row * 512 + c] = acc[mi][ni][r] + bias;
      }
  }
}

// ---------------- qkv GEMM fallback (small ws): reg-staged A, 128x128 ----------------

__global__ __launch_bounds__(256, 2) void qkv_gemm_rs(
    const float* __restrict__ X, const u16* __restrict__ WB,
    const float* __restrict__ QB, const float* __restrict__ VB,
    u16* __restrict__ QKV) {
  __shared__ u16 As[128 * 64];
  __shared__ u16 Bs[128 * 64];
  const int tid = threadIdx.x, lane = tid & 63, w = tid >> 6;
  int bid = blockIdx.x;
  int swz = (bid & 7) * 1536 + (bid >> 3);
  const int mt = swz / 12, nt = swz - mt * 12;
  const long m0 = (long)mt * 128, n0 = (long)nt * 128;
  const int wm = w >> 1, wn = w & 1;
  const f32x4 zf = {0.f, 0.f, 0.f, 0.f};

  f32x4 acc[4][4];
  #pragma unroll
  for (int mi = 0; mi < 4; ++mi)
    #pragma unroll
    for (int ni = 0; ni < 4; ++ni) acc[mi][ni] = zf;

  const int fr = lane & 15;
  const int fsw = ((lane >> 4) ^ (lane & 7)) * 8;
  const u16* Ap = &As[(wm * 64 + fr) * 64 + fsw];
  const u16* Bp = &Bs[(wn * 64 + fr) * 64 + fsw];

  for (int t = 0; t < 8; ++t) {
    float4 av[8];
    #pragma unroll
    for (int i = 0; i < 8; ++i) {
      int ch = tid + (i << 8);
      int row = ch >> 4, kc = ch & 15;
      av[i] = *(const float4*)&X[(m0 + row) * 512 + t * 64 + kc * 4];
    }
    #pragma unroll
    for (int i = 0; i < 4; ++i) {
      int ch = ((w << 2) + i) * 64 + lane;
      int row = ch >> 3, kc = (ch & 7) ^ (row & 7);
      gl_lds16(&WB[(n0 + row) * 512 + t * 64 + kc * 8], &Bs[((w << 2) + i) * 512]);
    }
    #pragma unroll
    for (int i = 0; i < 8; ++i) {
      int ch = tid + (i << 8);
      int row = ch >> 4, kc = ch & 15;
      int kcs = kc ^ ((row & 7) << 1);
      us4 u; u.x = f2bf(av[i].x); u.y = f2bf(av[i].y); u.z = f2bf(av[i].z); u.w = f2bf(av[i].w);
      *(us4*)&As[row * 64 + kcs * 4] = u;
    }
    __syncthreads();
    #pragma unroll
    for (int ks = 0; ks < 2; ++ks) {
      bf16x8 af[4], bfr[4];
      #pragma unroll
      for (int mi = 0; mi < 4; ++mi) af[mi] = ldswz(Ap + mi * 1024, ks);
      #pragma unroll
      for (int ni = 0; ni < 4; ++ni) bfr[ni] = ldswz(Bp + ni * 1024, ks);
      #pragma unroll
      for (int mi = 0; mi < 4; ++mi)
        #pragma unroll
        for (int ni = 0; ni < 4; ++ni)
          acc[mi][ni] = mfma16(af[mi], bfr[ni], acc[mi][ni]);
    }
    __syncthreads();
  }

  #pragma unroll
  for (int ni = 0; ni < 4; ++ni) {
    const long c = n0 + wn * 64 + ni * 16 + (lane & 15);
    float bias = (c < 512) ? QB[c] : (c < 1024 ? 0.f : VB[c - 1024]);
    #pragma unroll
    for (int mi = 0; mi < 4; ++mi)
      #pragma unroll
      for (int r = 0; r < 4; ++r) {
        long row = m0 + wm * 64 + mi * 16 + (lane >> 4) * 4 + r;
        QKV[row * 1536 + c] = f2bf(acc[mi][ni][r] + bias);
      }
  }
}

// ---------------- attention: 1 block per window, 4 waves coop per head ----------------

__global__ __launch_bounds__(256, 4) void attn_kernel(
    u16* __restrict__ QKV, const float* __restrict__ CMB, const float* __restrict__ LS) {
  __shared__ u16 sm[7424];       // 14848 B
  u16* qs = sm;                  // [64][40] (aliased by ps)
  u16* ksm = sm + 2560;          // [64][40] (aliased by ps)
  u16* ps = sm;                  // [64][72]
  u16* vt = sm + 5120;           // [32][72] (v transposed: [d][k])
  const int tid = threadIdx.x, lane = tid & 63, w = tid >> 6;
  const int b = blockIdx.x, wi = b & 15;
  const size_t base = (size_t)b * 64 * 1536;
  const int cl = lane & 15, lg = lane >> 4;
  const int srow = tid >> 2, sck = tid & 3;
  const int vd = tid & 31, vkb = tid >> 5;
  const f32x4 zf = {0.f, 0.f, 0.f, 0.f};

  for (int h = 0; h < 16; ++h) {
    const float scale = __expf(fminf(LS[h], 4.6051702f));
    {
      us8 qv = *(const us8*)&QKV[base + (size_t)srow * 1536 + h * 32 + sck * 8];
      float qf[8]; float ss = 0.f;
      #pragma unroll
      for (int j = 0; j < 8; ++j) { qf[j] = bf2f(qv[j]); ss += qf[j] * qf[j]; }
      ss += __shfl_xor(ss, 1); ss += __shfl_xor(ss, 2);
      float rn = scale / fmaxf(sqrtf(ss), 1e-12f);
      us8 qo;
      #pragma unroll
      for (int j = 0; j < 8; ++j) qo[j] = f2bf(qf[j] * rn);
      *(us8*)&qs[srow * 40 + sck * 8] = qo;
    }
    {
      us8 kv = *(const us8*)&QKV[base + (size_t)srow * 1536 + 512 + h * 32 + sck * 8];
      float kf[8]; float ss = 0.f;
      #pragma unroll
      for (int j = 0; j < 8; ++j) { kf[j] = bf2f(kv[j]); ss += kf[j] * kf[j]; }
      ss += __shfl_xor(ss, 1); ss += __shfl_xor(ss, 2);
      float rn = 1.f / fmaxf(sqrtf(ss), 1e-12f);
      us8 ko;
      #pragma unroll
      for (int j = 0; j < 8; ++j) ko[j] = f2bf(kf[j] * rn);
      *(us8*)&ksm[srow * 40 + sck * 8] = ko;
    }
    {
      us8 vo;
      #pragma unroll
      for (int e = 0; e < 8; ++e)
        vo[e] = QKV[base + (size_t)(vkb * 8 + e) * 1536 + 1024 + h * 32 + vd];
      *(us8*)&vt[vd * 72 + vkb * 8] = vo;
    }
    __syncthreads();

    bf16x8 aq = *(const bf16x8*)&qs[(w * 16 + cl) * 40 + lg * 8];
    f32x4 s4[4];
    #pragma unroll
    for (int nt = 0; nt < 4; ++nt) {
      bf16x8 bk = *(const bf16x8*)&ksm[(nt * 16 + cl) * 40 + lg * 8];
      s4[nt] = mfma16(aq, bk, zf);
    }

    const float* cp = &CMB[((size_t)(wi * 16 + h)) << 12];
    const int r0 = w * 16 + lg * 4;
    float p[4][4];
    #pragma unroll
    for (int r = 0; r < 4; ++r) {
      float mx = -3.0e38f;
      #pragma unroll
      for (int q4 = 0; q4 < 4; ++q4) {
        float v = s4[q4][r] + cp[(r0 + r) * 64 + q4 * 16 + cl];
        p[q4][r] = v; mx = fmaxf(mx, v);
      }
      mx = fmaxf(mx, __shfl_xor(mx, 1));
      mx = fmaxf(mx, __shfl_xor(mx, 2));
      mx = fmaxf(mx, __shfl_xor(mx, 4));
      mx = fmaxf(mx, __shfl_xor(mx, 8));
      float sum = 0.f;
      #pragma unroll
      for (int q4 = 0; q4 < 4; ++q4) { float e = __expf(p[q4][r] - mx); p[q4][r] = e; sum += e; }
      sum += __shfl_xor(sum, 1); sum += __shfl_xor(sum, 2);
      sum += __shfl_xor(sum, 4); sum += __shfl_xor(sum, 8);
      float inv = 1.f / sum;
      #pragma unroll
      for (int q4 = 0; q4 < 4; ++q4) p[q4][r] *= inv;
    }
    __syncthreads();

    #pragma unroll
    for (int r = 0; r < 4; ++r)
      #pragma unroll
      for (int q4 = 0; q4 < 4; ++q4)
        ps[(r0 + r) * 72 + q4 * 16 + cl] = f2bf(p[q4][r]);

    f32x4 o4[2]; o4[0] = zf; o4[1] = zf;
    #pragma unroll
    for (int ks = 0; ks < 2; ++ks) {
      bf16x8 ap = *(const bf16x8*)&ps[(w * 16 + cl) * 72 + ks * 32 + lg * 8];
      #pragma unroll
      for (int n2 = 0; n2 < 2; ++n2) {
        bf16x8 bv = *(const bf16x8*)&vt[(n2 * 16 + cl) * 72 + ks * 32 + lg * 8];
        o4[n2] = mfma16(ap, bv, o4[n2]);
      }
    }
    #pragma unroll
    for (int n2 = 0; n2 < 2; ++n2)
      #pragma unroll
      for (int r = 0; r < 4; ++r)
        QKV[base + (size_t)(w * 16 + lg * 4 + r) * 1536 + h * 32 + n2 * 16 + cl] = f2bf(o4[n2][r]);
    __syncthreads();
  }
}

// ---------------- launch ----------------

extern "C" void kernel_launch(void* const* d_in, const int* in_sizes, int n_in,
                              void* d_out, int out_size, void* d_ws, size_t ws_size,
                              hipStream_t stream) {
  const float* X    = (const float*)d_in[0];
  const float* MASK = (const float*)d_in[1];
  const float* QW   = (const float*)d_in[2];
  const float* QB   = (const float*)d_in[3];
  const float* VB   = (const float*)d_in[4];
  const float* LS   = (const float*)d_in[5];
  const float* CW1  = (const float*)d_in[6];
  const float* CB1  = (const float*)d_in[7];
  const float* CW2  = (const float*)d_in[8];
  const float* PW   = (const float*)d_in[9];
  const float* PB   = (const float*)d_in[10];
  const float* CT   = (const float*)d_in[11];
  const int*   RPI  = (const int*)d_in[12];
  float* OUT = (float*)d_out;

  char* ws = (char*)d_ws;
  const bool big = ws_size >= 543178752ull;
  u16* QKV = (u16*)ws;                                    // 402,653,184 B
  u16* XB  = (u16*)(ws + 402653184ull);                   // 134,217,728 B (big only)
  size_t off = big ? 536870912ull : 402653184ull;
  float* CMB = (float*)(ws + off);  off += 4194304ull;    // 4 MB
  float* SIG = (float*)(ws + off);  off += 16384ull;
  u16*   WQB = (u16*)(ws + off);    off += 1572864ull;
  u16*   WPB = (u16*)(ws + off);

  conv_w_kernel<<<1024, 256, 0, stream>>>(QW, PW, WQB, WPB);
  sig16_kernel<<<225, 256, 0, stream>>>(CT, CW1, CB1, CW2, SIG);
  cmb_kernel<<<256, 256, 0, stream>>>(SIG, MASK, RPI, CMB);
  if (big) {
    xconv_kernel<<<32768, 256, 0, stream>>>(X, XB);
    qkv_gemm8<<<3072, 512, 0, stream>>>(XB, WQB, QB, VB, QKV);
  } else {
    qkv_gemm_rs<<<12288, 256, 0, stream>>>(X, WQB, QB, VB, QKV);
  }
  attn_kernel<<<2048, 256, 0, stream>>>(QKV, CMB, LS);
  proj_gemm8<<<1024, 512, 0, stream>>>(QKV, WPB, PB, OUT);
}

// Round 7
// 760.591 us; speedup vs baseline: 1.3191x; 1.3191x over previous
//
#include <hip/hip_runtime.h>
#include <stdint.h>
#include <stddef.h>

// SwinV2-B stage-3 window attention, MI355X bf16-MFMA pipeline.
// Round 7: restore trailing barrier (r6 regression: desync -> L2 write thrash,
// WRITE x2 / FETCH +400MB), revert proj to round-2 form, split dependent
// MFMA pairs into two independent sweeps.
// Big ws layout (ws_size >= 543,178,752 B):
//   [0)            QKV bf16 [131072][1536]
//   [402653184)    XB  bf16 [131072][512]
//   [536870912)    CMB f32 [16w][16h][64][64]
//   [541065216)    SIG f32 [225][16] (pad 16K)
//   [541081600)    WQB bf16 [1536][512]
//   [542654464)    WPB bf16 [512][512]

typedef __attribute__((ext_vector_type(8))) short bf16x8;
typedef __attribute__((ext_vector_type(4))) float f32x4;
typedef __attribute__((ext_vector_type(4))) unsigned short us4;
typedef __attribute__((ext_vector_type(8))) unsigned short us8;
typedef unsigned short u16;
typedef unsigned int u32;

#define FENCE() asm volatile("" ::: "memory")
#define WAITV4() asm volatile("s_waitcnt vmcnt(4)" ::: "memory")
#define WAITV0() asm volatile("s_waitcnt vmcnt(0)" ::: "memory")
#define WAITL0() asm volatile("s_waitcnt lgkmcnt(0)" ::: "memory")

__device__ __forceinline__ u16 f2bf(float f) {
  union { __bf16 b; u16 u; } cv;
  cv.b = (__bf16)f;            // hardware RNE convert on gfx950
  return cv.u;
}
__device__ __forceinline__ float bf2f(u16 s) {
  return __uint_as_float(((u32)s) << 16);
}
__device__ __forceinline__ void gl_lds16(const void* g, void* l) {
  __builtin_amdgcn_global_load_lds(
      (const __attribute__((address_space(1))) u32*)g,
      (__attribute__((address_space(3))) u32*)l, 16, 0, 0);
}
__device__ __forceinline__ f32x4 mfma16(bf16x8 a, bf16x8 b, f32x4 c) {
  return __builtin_amdgcn_mfma_f32_16x16x32_bf16(a, b, c, 0, 0, 0);
}
__device__ __forceinline__ bf16x8 ldswz(const u16* p, int ks) {
  return *(const bf16x8*)((const u16*)((uintptr_t)p ^ (uintptr_t)(ks << 6)));
}

// ---------------- prep kernels ----------------

__global__ void conv_w_kernel(const float* __restrict__ QW, const float* __restrict__ PW,
                              u16* __restrict__ WQB, u16* __restrict__ WPB) {
  int idx = blockIdx.x * 256 + threadIdx.x;   // 262144 float4 chunks total
  const int NQ = 1536 * 512 / 4;              // 196608
  float4 v; u16* dst;
  if (idx < NQ) { v = ((const float4*)QW)[idx]; dst = WQB + (size_t)idx * 4; }
  else { int k = idx - NQ; v = ((const float4*)PW)[k]; dst = WPB + (size_t)k * 4; }
  us4 u; u.x = f2bf(v.x); u.y = f2bf(v.y); u.z = f2bf(v.z); u.w = f2bf(v.w);
  *(us4*)dst = u;
}

__global__ void xconv_kernel(const float* __restrict__ X, u16* __restrict__ XB) {
  size_t idx = (size_t)blockIdx.x * 256 + threadIdx.x;   // 8,388,608 threads, 8 f32 each
  float4 a = ((const float4*)X)[idx * 2];
  float4 b = ((const float4*)X)[idx * 2 + 1];
  us8 o;
  o[0] = f2bf(a.x); o[1] = f2bf(a.y); o[2] = f2bf(a.z); o[3] = f2bf(a.w);
  o[4] = f2bf(b.x); o[5] = f2bf(b.y); o[6] = f2bf(b.z); o[7] = f2bf(b.w);
  *(us8*)&XB[idx * 8] = o;
}

__global__ void sig16_kernel(const float* __restrict__ CT, const float* __restrict__ W1,
                             const float* __restrict__ B1, const float* __restrict__ W2,
                             float* __restrict__ SIG) {
  int i = blockIdx.x;            // 0..224
  int tid = threadIdx.x;         // 256
  float c0 = CT[i * 2 + 0], c1 = CT[i * 2 + 1];
  float a[16];
  #pragma unroll
  for (int hh = 0; hh < 16; ++hh) a[hh] = 0.f;
  #pragma unroll
  for (int jj = 0; jj < 2; ++jj) {
    int j = tid + jj * 256;
    float h = fmaxf(c0 * W1[j * 2 + 0] + c1 * W1[j * 2 + 1] + B1[j], 0.f);
    #pragma unroll
    for (int hh = 0; hh < 16; ++hh) a[hh] += h * W2[hh * 512 + j];
  }
  __shared__ float red[4][16];
  #pragma unroll
  for (int hh = 0; hh < 16; ++hh) {
    float v = a[hh];
    for (int m = 1; m < 64; m <<= 1) v += __shfl_xor(v, m);
    if ((tid & 63) == 0) red[tid >> 6][hh] = v;
  }
  __syncthreads();
  if (tid < 16) {
    float v = red[0][tid] + red[1][tid] + red[2][tid] + red[3][tid];
    SIG[i * 16 + tid] = 16.f / (1.f + __expf(-v));
  }
}

__global__ void cmb_kernel(const float* __restrict__ SIG, const float* __restrict__ MASK,
                           const int* __restrict__ RPI, float* __restrict__ CMB) {
  int b = blockIdx.x;            // (w,h) = 256 blocks
  int w = b >> 4, h = b & 15;
  int tid = threadIdx.x;
  const float* mrow = &MASK[(size_t)w * 4096];
  float* crow = &CMB[(size_t)b * 4096];
  #pragma unroll
  for (int it = 0; it < 16; ++it) {
    int nm = it * 256 + tid;
    crow[nm] = SIG[RPI[nm] * 16 + h] + mrow[nm];
  }
}

// ============ 256x256/8-wave zigzag pipeline (macro body) ============
// Phase: { ds_reads | stage issue | (vmcnt) } -> barrier -> lgkm(0) -> MFMA -> barrier.
// Stages: P0->B1(t+1), P1->A1(t+1), P2->A0(t+2), P3->B0(t+2)+vmcnt(4).
// MFMA split into two sweeps (af0xB0 all 8 (m,n), then af1xB1) so no
// back-to-back dependent MFMAs; per-acc accumulation order unchanged.

#define MFMA_QUAD(MB, NB, B0, B1)                                          \
  FENCE(); __builtin_amdgcn_s_barrier(); FENCE();                          \
  WAITL0(); __builtin_amdgcn_sched_barrier(0);                             \
  __builtin_amdgcn_s_setprio(1);                                           \
  _Pragma("unroll")                                                        \
  for (int m = 0; m < 4; ++m)                                              \
    _Pragma("unroll")                                                      \
    for (int n = 0; n < 2; ++n)                                            \
      acc[(MB) + m][(NB) + n] = mfma16(af0[m], B0[n], acc[(MB) + m][(NB) + n]); \
  _Pragma("unroll")                                                        \
  for (int m = 0; m < 4; ++m)                                              \
    _Pragma("unroll")                                                      \
    for (int n = 0; n < 2; ++n)                                            \
      acc[(MB) + m][(NB) + n] = mfma16(af1[m], B1[n], acc[(MB) + m][(NB) + n]); \
  __builtin_amdgcn_s_setprio(0);                                           \
  FENCE(); __builtin_amdgcn_s_barrier(); FENCE();

#define GEMM8_KLOOP()                                                      \
  for (int t = 0; t < 8; ++t) {                                            \
    const int buf = (t & 1) * 32768;                                       \
    /* P0 */                                                               \
    _Pragma("unroll")                                                      \
    for (int m = 0; m < 4; ++m) {                                          \
      const u16* pA = &S[buf + (wm * 64 + m * 16 + fr) * 64 + fsw];        \
      af0[m] = ldswz(pA, 0); af1[m] = ldswz(pA, 1);                        \
    }                                                                      \
    _Pragma("unroll")                                                      \
    for (int n = 0; n < 2; ++n) {                                          \
      const u16* pB = &S[buf + 16384 + (wn * 32 + n * 16 + fr) * 64 + fsw];\
      b00[n] = ldswz(pB, 0); b01[n] = ldswz(pB, 1);                        \
    }                                                                      \
    if (t < 7) stageB(t + 1, 1);                                           \
    MFMA_QUAD(0, 0, b00, b01)                                              \
    /* P1 */                                                               \
    _Pragma("unroll")                                                      \
    for (int n = 0; n < 2; ++n) {                                          \
      const u16* pB = &S[buf + 16384 + (128 + wn * 32 + n * 16 + fr) * 64 + fsw]; \
      b10[n] = ldswz(pB, 0); b11[n] = ldswz(pB, 1);                        \
    }                                                                      \
    if (t < 7) stageA(t + 1, 1);                                           \
    MFMA_QUAD(0, 2, b10, b11)                                              \
    /* P2 */                                                               \
    _Pragma("unroll")                                                      \
    for (int m = 0; m < 4; ++m) {                                          \
      const u16* pA = &S[buf + (128 + wm * 64 + m * 16 + fr) * 64 + fsw];  \
      af0[m] = ldswz(pA, 0); af1[m] = ldswz(pA, 1);                        \
    }                                                                      \
    if (t < 6) stageA(t + 2, 0);                                           \
    MFMA_QUAD(4, 2, b10, b11)                                              \
    /* P3 */                                                               \
    if (t < 6) { stageB(t + 2, 0); WAITV4(); }                             \
    else if (t == 6) { WAITV0(); }                                         \
    MFMA_QUAD(4, 0, b00, b01)                                              \
  }

// ---------------- qkv GEMM: XB bf16 [131072,512] @ WQB^T -> bf16 [131072,1536] ----

__global__ __launch_bounds__(512, 1) void qkv_gemm8(
    const u16* __restrict__ XB, const u16* __restrict__ WB,
    const float* __restrict__ QB, const float* __restrict__ VB,
    u16* __restrict__ QKV) {
  __shared__ u16 S[65536];  // [buf:2][ A[256][64] | B[256][64] ]  131072 B
  const int tid = threadIdx.x, lane = tid & 63, w = tid >> 6;
  int bid = blockIdx.x;                           // 3072 = 512m x 6n
  int swz = (bid & 7) * 384 + (bid >> 3);         // bijective XCD swizzle
  const int mt = swz / 6, nt = swz - mt * 6;
  const long m0 = (long)mt * 256, n0 = (long)nt * 256;
  const int wm = w >> 2, wn = w & 3;
  const int fr = lane & 15, lg = lane >> 4;
  const int fsw = (lg ^ (lane & 7)) << 3;
  const f32x4 zf = {0.f, 0.f, 0.f, 0.f};

  f32x4 acc[8][4];
  #pragma unroll
  for (int mi = 0; mi < 8; ++mi)
    #pragma unroll
    for (int ni = 0; ni < 4; ++ni) acc[mi][ni] = zf;

  auto stageA = [&](int kt, int h) {
    int dst = (kt & 1) * 32768 + h * 8192;
    #pragma unroll
    for (int i = 0; i < 2; ++i) {
      int ch = i * 512 + tid;
      int row = ch >> 3, kcs = (ch & 7) ^ (row & 7);
      gl_lds16(&XB[(size_t)(m0 + h * 128 + row) * 512 + kt * 64 + kcs * 8],
               &S[dst + (i * 512 + w * 64) * 8]);
    }
  };
  auto stageB = [&](int kt, int h) {
    int dst = (kt & 1) * 32768 + 16384 + h * 8192;
    #pragma unroll
    for (int i = 0; i < 2; ++i) {
      int ch = i * 512 + tid;
      int row = ch >> 3, kcs = (ch & 7) ^ (row & 7);
      gl_lds16(&WB[(size_t)(n0 + h * 128 + row) * 512 + kt * 64 + kcs * 8],
               &S[dst + (i * 512 + w * 64) * 8]);
    }
  };

  bf16x8 af0[4], af1[4], b00[2], b01[2], b10[2], b11[2];

  stageA(0, 0); stageB(0, 0); stageB(0, 1); stageA(0, 1);
  stageA(1, 0); stageB(1, 0);
  WAITV4();
  FENCE(); __builtin_amdgcn_s_barrier(); FENCE();

  GEMM8_KLOOP()

  #pragma unroll
  for (int ni = 0; ni < 4; ++ni) {
    const long c = n0 + (ni >> 1) * 128 + wn * 32 + (ni & 1) * 16 + fr;
    float bias = (c < 512) ? QB[c] : (c < 1024 ? 0.f : VB[c - 1024]);
    #pragma unroll
    for (int mi = 0; mi < 8; ++mi)
      #pragma unroll
      for (int r = 0; r < 4; ++r) {
        long row = m0 + (mi >> 2) * 128 + wm * 64 + (mi & 3) * 16 + lg * 4 + r;
        QKV[row * 1536 + c] = f2bf(acc[mi][ni][r] + bias);
      }
  }
}

// ---------------- proj GEMM (round-2): bf16 [131072,512](lda=1536) @ WPB^T + b -> f32 ----

__global__ __launch_bounds__(256, 2) void proj_gemm(
    const u16* __restrict__ A, const u16* __restrict__ WB,
    const float* __restrict__ PB, float* __restrict__ OUT) {
  __shared__ u16 As[128 * 64];
  __shared__ u16 Bs[128 * 64];
  const int tid = threadIdx.x, lane = tid & 63, w = tid >> 6;
  int bid = blockIdx.x;
  int swz = (bid & 7) * 512 + (bid >> 3);
  const int mt = swz >> 2, nt = swz & 3;
  const long m0 = (long)mt * 128, n0 = (long)nt * 128;
  const int wm = w >> 1, wn = w & 1;
  const f32x4 zf = {0.f, 0.f, 0.f, 0.f};

  f32x4 acc[4][4];
  #pragma unroll
  for (int mi = 0; mi < 4; ++mi)
    #pragma unroll
    for (int ni = 0; ni < 4; ++ni) acc[mi][ni] = zf;

  const int fr = lane & 15;
  const int fsw = ((lane >> 4) ^ (lane & 7)) * 8;
  const u16* Ap = &As[(wm * 64 + fr) * 64 + fsw];
  const u16* Bp = &Bs[(wn * 64 + fr) * 64 + fsw];

  for (int t = 0; t < 8; ++t) {
    #pragma unroll
    for (int i = 0; i < 4; ++i) {
      int ch = ((w << 2) + i) * 64 + lane;
      int row = ch >> 3, kc = (ch & 7) ^ (row & 7);
      gl_lds16(&A[(m0 + row) * 1536 + t * 64 + kc * 8], &As[((w << 2) + i) * 512]);
      gl_lds16(&WB[(n0 + row) * 512 + t * 64 + kc * 8], &Bs[((w << 2) + i) * 512]);
    }
    __syncthreads();
    #pragma unroll
    for (int ks = 0; ks < 2; ++ks) {
      bf16x8 af[4], bfr[4];
      #pragma unroll
      for (int mi = 0; mi < 4; ++mi) af[mi] = ldswz(Ap + mi * 1024, ks);
      #pragma unroll
      for (int ni = 0; ni < 4; ++ni) bfr[ni] = ldswz(Bp + ni * 1024, ks);
      #pragma unroll
      for (int mi = 0; mi < 4; ++mi)
        #pragma unroll
        for (int ni = 0; ni < 4; ++ni)
          acc[mi][ni] = mfma16(af[mi], bfr[ni], acc[mi][ni]);
    }
    __syncthreads();
  }

  #pragma unroll
  for (int ni = 0; ni < 4; ++ni) {
    const long c = n0 + wn * 64 + ni * 16 + fr;
    float bias = PB[c];
    #pragma unroll
    for (int mi = 0; mi < 4; ++mi)
      #pragma unroll
      for (int r = 0; r < 4; ++r) {
        long row = m0 + wm * 64 + mi * 16 + (lane >> 4) * 4 + r;
        OUT[row * 512 + c] = acc[mi][ni][r] + bias;
      }
  }
}

// ---------------- qkv GEMM fallback (small ws): reg-staged A, 128x128 ----------------

__global__ __launch_bounds__(256, 2) void qkv_gemm_rs(
    const float* __restrict__ X, const u16* __restrict__ WB,
    const float* __restrict__ QB, const float* __restrict__ VB,
    u16* __restrict__ QKV) {
  __shared__ u16 As[128 * 64];
  __shared__ u16 Bs[128 * 64];
  const int tid = threadIdx.x, lane = tid & 63, w = tid >> 6;
  int bid = blockIdx.x;
  int swz = (bid & 7) * 1536 + (bid >> 3);
  const int mt = swz / 12, nt = swz - mt * 12;
  const long m0 = (long)mt * 128, n0 = (long)nt * 128;
  const int wm = w >> 1, wn = w & 1;
  const f32x4 zf = {0.f, 0.f, 0.f, 0.f};

  f32x4 acc[4][4];
  #pragma unroll
  for (int mi = 0; mi < 4; ++mi)
    #pragma unroll
    for (int ni = 0; ni < 4; ++ni) acc[mi][ni] = zf;

  const int fr = lane & 15;
  const int fsw = ((lane >> 4) ^ (lane & 7)) * 8;
  const u16* Ap = &As[(wm * 64 + fr) * 64 + fsw];
  const u16* Bp = &Bs[(wn * 64 + fr) * 64 + fsw];

  for (int t = 0; t < 8; ++t) {
    float4 av[8];
    #pragma unroll
    for (int i = 0; i < 8; ++i) {
      int ch = tid + (i << 8);
      int row = ch >> 4, kc = ch & 15;
      av[i] = *(const float4*)&X[(m0 + row) * 512 + t * 64 + kc * 4];
    }
    #pragma unroll
    for (int i = 0; i < 4; ++i) {
      int ch = ((w << 2) + i) * 64 + lane;
      int row = ch >> 3, kc = (ch & 7) ^ (row & 7);
      gl_lds16(&WB[(n0 + row) * 512 + t * 64 + kc * 8], &Bs[((w << 2) + i) * 512]);
    }
    #pragma unroll
    for (int i = 0; i < 8; ++i) {
      int ch = tid + (i << 8);
      int row = ch >> 4, kc = ch & 15;
      int kcs = kc ^ ((row & 7) << 1);
      us4 u; u.x = f2bf(av[i].x); u.y = f2bf(av[i].y); u.z = f2bf(av[i].z); u.w = f2bf(av[i].w);
      *(us4*)&As[row * 64 + kcs * 4] = u;
    }
    __syncthreads();
    #pragma unroll
    for (int ks = 0; ks < 2; ++ks) {
      bf16x8 af[4], bfr[4];
      #pragma unroll
      for (int mi = 0; mi < 4; ++mi) af[mi] = ldswz(Ap + mi * 1024, ks);
      #pragma unroll
      for (int ni = 0; ni < 4; ++ni) bfr[ni] = ldswz(Bp + ni * 1024, ks);
      #pragma unroll
      for (int mi = 0; mi < 4; ++mi)
        #pragma unroll
        for (int ni = 0; ni < 4; ++ni)
          acc[mi][ni] = mfma16(af[mi], bfr[ni], acc[mi][ni]);
    }
    __syncthreads();
  }

  #pragma unroll
  for (int ni = 0; ni < 4; ++ni) {
    const long c = n0 + wn * 64 + ni * 16 + (lane & 15);
    float bias = (c < 512) ? QB[c] : (c < 1024 ? 0.f : VB[c - 1024]);
    #pragma unroll
    for (int mi = 0; mi < 4; ++mi)
      #pragma unroll
      for (int r = 0; r < 4; ++r) {
        long row = m0 + wm * 64 + mi * 16 + (lane >> 4) * 4 + r;
        QKV[row * 1536 + c] = f2bf(acc[mi][ni][r] + bias);
      }
  }
}

// ---------------- attention: 1 block per window, 4 waves coop per head ----------------

__global__ __launch_bounds__(256, 4) void attn_kernel(
    u16* __restrict__ QKV, const float* __restrict__ CMB, const float* __restrict__ LS) {
  __shared__ u16 sm[7424];       // 14848 B
  u16* qs = sm;                  // [64][40] (aliased by ps)
  u16* ksm = sm + 2560;          // [64][40] (aliased by ps)
  u16* ps = sm;                  // [64][72]
  u16* vt = sm + 5120;           // [32][72] (v transposed: [d][k])
  const int tid = threadIdx.x, lane = tid & 63, w = tid >> 6;
  const int b = blockIdx.x, wi = b & 15;
  const size_t base = (size_t)b * 64 * 1536;
  const int cl = lane & 15, lg = lane >> 4;
  const int srow = tid >> 2, sck = tid & 3;
  const int vd = tid & 31, vkb = tid >> 5;
  const f32x4 zf = {0.f, 0.f, 0.f, 0.f};

  for (int h = 0; h < 16; ++h) {
    const float scale = __expf(fminf(LS[h], 4.6051702f));
    {
      us8 qv = *(const us8*)&QKV[base + (size_t)srow * 1536 + h * 32 + sck * 8];
      float qf[8]; float ss = 0.f;
      #pragma unroll
      for (int j = 0; j < 8; ++j) { qf[j] = bf2f(qv[j]); ss += qf[j] * qf[j]; }
      ss += __shfl_xor(ss, 1); ss += __shfl_xor(ss, 2);
      float rn = scale / fmaxf(sqrtf(ss), 1e-12f);
      us8 qo;
      #pragma unroll
      for (int j = 0; j < 8; ++j) qo[j] = f2bf(qf[j] * rn);
      *(us8*)&qs[srow * 40 + sck * 8] = qo;
    }
    {
      us8 kv = *(const us8*)&QKV[base + (size_t)srow * 1536 + 512 + h * 32 + sck * 8];
      float kf[8]; float ss = 0.f;
      #pragma unroll
      for (int j = 0; j < 8; ++j) { kf[j] = bf2f(kv[j]); ss += kf[j] * kf[j]; }
      ss += __shfl_xor(ss, 1); ss += __shfl_xor(ss, 2);
      float rn = 1.f / fmaxf(sqrtf(ss), 1e-12f);
      us8 ko;
      #pragma unroll
      for (int j = 0; j < 8; ++j) ko[j] = f2bf(kf[j] * rn);
      *(us8*)&ksm[srow * 40 + sck * 8] = ko;
    }
    {
      us8 vo;
      #pragma unroll
      for (int e = 0; e < 8; ++e)
        vo[e] = QKV[base + (size_t)(vkb * 8 + e) * 1536 + 1024 + h * 32 + vd];
      *(us8*)&vt[vd * 72 + vkb * 8] = vo;
    }
    __syncthreads();

    bf16x8 aq = *(const bf16x8*)&qs[(w * 16 + cl) * 40 + lg * 8];
    f32x4 s4[4];
    #pragma unroll
    for (int nt = 0; nt < 4; ++nt) {
      bf16x8 bk = *(const bf16x8*)&ksm[(nt * 16 + cl) * 40 + lg * 8];
      s4[nt] = mfma16(aq, bk, zf);
    }

    const float* cp = &CMB[((size_t)(wi * 16 + h)) << 12];
    const int r0 = w * 16 + lg * 4;
    float p[4][4];
    #pragma unroll
    for (int r = 0; r < 4; ++r) {
      float mx = -3.0e38f;
      #pragma unroll
      for (int q4 = 0; q4 < 4; ++q4) {
        float v = s4[q4][r] + cp[(r0 + r) * 64 + q4 * 16 + cl];
        p[q4][r] = v; mx = fmaxf(mx, v);
      }
      mx = fmaxf(mx, __shfl_xor(mx, 1));
      mx = fmaxf(mx, __shfl_xor(mx, 2));
      mx = fmaxf(mx, __shfl_xor(mx, 4));
      mx = fmaxf(mx, __shfl_xor(mx, 8));
      float sum = 0.f;
      #pragma unroll
      for (int q4 = 0; q4 < 4; ++q4) { float e = __expf(p[q4][r] - mx); p[q4][r] = e; sum += e; }
      sum += __shfl_xor(sum, 1); sum += __shfl_xor(sum, 2);
      sum += __shfl_xor(sum, 4); sum += __shfl_xor(sum, 8);
      float inv = 1.f / sum;
      #pragma unroll
      for (int q4 = 0; q4 < 4; ++q4) p[q4][r] *= inv;
    }
    __syncthreads();

    #pragma unroll
    for (int r = 0; r < 4; ++r)
      #pragma unroll
      for (int q4 = 0; q4 < 4; ++q4)
        ps[(r0 + r) * 72 + q4 * 16 + cl] = f2bf(p[q4][r]);

    f32x4 o4[2]; o4[0] = zf; o4[1] = zf;
    #pragma unroll
    for (int ks = 0; ks < 2; ++ks) {
      bf16x8 ap = *(const bf16x8*)&ps[(w * 16 + cl) * 72 + ks * 32 + lg * 8];
      #pragma unroll
      for (int n2 = 0; n2 < 2; ++n2) {
        bf16x8 bv = *(const bf16x8*)&vt[(n2 * 16 + cl) * 72 + ks * 32 + lg * 8];
        o4[n2] = mfma16(ap, bv, o4[n2]);
      }
    }
    #pragma unroll
    for (int n2 = 0; n2 < 2; ++n2)
      #pragma unroll
      for (int r = 0; r < 4; ++r)
        QKV[base + (size_t)(w * 16 + lg * 4 + r) * 1536 + h * 32 + n2 * 16 + cl] = f2bf(o4[n2][r]);
    __syncthreads();
  }
}

// ---------------- launch ----------------

extern "C" void kernel_launch(void* const* d_in, const int* in_sizes, int n_in,
                              void* d_out, int out_size, void* d_ws, size_t ws_size,
                              hipStream_t stream) {
  const float* X    = (const float*)d_in[0];
  const float* MASK = (const float*)d_in[1];
  const float* QW   = (const float*)d_in[2];
  const float* QB   = (const float*)d_in[3];
  const float* VB   = (const float*)d_in[4];
  const float* LS   = (const float*)d_in[5];
  const float* CW1  = (const float*)d_in[6];
  const float* CB1  = (const float*)d_in[7];
  const float* CW2  = (const float*)d_in[8];
  const float* PW   = (const float*)d_in[9];
  const float* PB   = (const float*)d_in[10];
  const float* CT   = (const float*)d_in[11];
  const int*   RPI  = (const int*)d_in[12];
  float* OUT = (float*)d_out;

  char* ws = (char*)d_ws;
  const bool big = ws_size >= 543178752ull;
  u16* QKV = (u16*)ws;                                    // 402,653,184 B
  u16* XB  = (u16*)(ws + 402653184ull);                   // 134,217,728 B (big only)
  size_t off = big ? 536870912ull : 402653184ull;
  float* CMB = (float*)(ws + off);  off += 4194304ull;    // 4 MB
  float* SIG = (float*)(ws + off);  off += 16384ull;
  u16*   WQB = (u16*)(ws + off);    off += 1572864ull;
  u16*   WPB = (u16*)(ws + off);

  conv_w_kernel<<<1024, 256, 0, stream>>>(QW, PW, WQB, WPB);
  sig16_kernel<<<225, 256, 0, stream>>>(CT, CW1, CB1, CW2, SIG);
  cmb_kernel<<<256, 256, 0, stream>>>(SIG, MASK, RPI, CMB);
  if (big) {
    xconv_kernel<<<32768, 256, 0, stream>>>(X, XB);
    qkv_gemm8<<<3072, 512, 0, stream>>>(XB, WQB, QB, VB, QKV);
  } else {
    qkv_gemm_rs<<<12288, 256, 0, stream>>>(X, WQB, QB, VB, QKV);
  }
  attn_kernel<<<2048, 256, 0, stream>>>(QKV, CMB, LS);
  proj_gemm<<<4096, 256, 0, stream>>>(QKV, WPB, PB, OUT);
}

// Round 8
// 680.653 us; speedup vs baseline: 1.4740x; 1.1174x over previous
//
#include <hip/hip_runtime.h>
#include <stdint.h>
#include <stddef.h>

// SwinV2-B stage-3 window attention, MI355X bf16-MFMA pipeline.
// Round 8: 128x256 tile, BK=32, triple-buffered 72KB LDS, 2 blocks/CU
// (cross-block overlap fills barrier/latency gaps), counted vmcnt rotation.
// Big ws layout (ws_size >= 543,178,752 B):
//   [0)            QKV bf16 [131072][1536]
//   [402653184)    XB  bf16 [131072][512]
//   [536870912)    CMB f32 [16w][16h][64][64]
//   [541065216)    SIG f32 [225][16] (pad 16K)
//   [541081600)    WQB bf16 [1536][512]
//   [542654464)    WPB bf16 [512][512]

typedef __attribute__((ext_vector_type(8))) short bf16x8;
typedef __attribute__((ext_vector_type(4))) float f32x4;
typedef __attribute__((ext_vector_type(4))) unsigned short us4;
typedef __attribute__((ext_vector_type(8))) unsigned short us8;
typedef unsigned short u16;
typedef unsigned int u32;

#define FENCE() asm volatile("" ::: "memory")
#define WAITV4() asm volatile("s_waitcnt vmcnt(4)" ::: "memory")
#define WAITV3() asm volatile("s_waitcnt vmcnt(3)" ::: "memory")
#define WAITV0() asm volatile("s_waitcnt vmcnt(0)" ::: "memory")
#define WAITL0() asm volatile("s_waitcnt lgkmcnt(0)" ::: "memory")

__device__ __forceinline__ u16 f2bf(float f) {
  union { __bf16 b; u16 u; } cv;
  cv.b = (__bf16)f;            // hardware RNE convert on gfx950
  return cv.u;
}
__device__ __forceinline__ float bf2f(u16 s) {
  return __uint_as_float(((u32)s) << 16);
}
__device__ __forceinline__ void gl_lds16(const void* g, void* l) {
  __builtin_amdgcn_global_load_lds(
      (const __attribute__((address_space(1))) u32*)g,
      (__attribute__((address_space(3))) u32*)l, 16, 0, 0);
}
__device__ __forceinline__ f32x4 mfma16(bf16x8 a, bf16x8 b, f32x4 c) {
  return __builtin_amdgcn_mfma_f32_16x16x32_bf16(a, b, c, 0, 0, 0);
}
__device__ __forceinline__ bf16x8 ldswz(const u16* p, int ks) {
  return *(const bf16x8*)((const u16*)((uintptr_t)p ^ (uintptr_t)(ks << 6)));
}

// ---------------- prep kernels ----------------

__global__ void conv_w_kernel(const float* __restrict__ QW, const float* __restrict__ PW,
                              u16* __restrict__ WQB, u16* __restrict__ WPB) {
  int idx = blockIdx.x * 256 + threadIdx.x;   // 262144 float4 chunks total
  const int NQ = 1536 * 512 / 4;              // 196608
  float4 v; u16* dst;
  if (idx < NQ) { v = ((const float4*)QW)[idx]; dst = WQB + (size_t)idx * 4; }
  else { int k = idx - NQ; v = ((const float4*)PW)[k]; dst = WPB + (size_t)k * 4; }
  us4 u; u.x = f2bf(v.x); u.y = f2bf(v.y); u.z = f2bf(v.z); u.w = f2bf(v.w);
  *(us4*)dst = u;
}

__global__ void xconv_kernel(const float* __restrict__ X, u16* __restrict__ XB) {
  size_t idx = (size_t)blockIdx.x * 256 + threadIdx.x;   // 8,388,608 threads, 8 f32 each
  float4 a = ((const float4*)X)[idx * 2];
  float4 b = ((const float4*)X)[idx * 2 + 1];
  us8 o;
  o[0] = f2bf(a.x); o[1] = f2bf(a.y); o[2] = f2bf(a.z); o[3] = f2bf(a.w);
  o[4] = f2bf(b.x); o[5] = f2bf(b.y); o[6] = f2bf(b.z); o[7] = f2bf(b.w);
  *(us8*)&XB[idx * 8] = o;
}

__global__ void sig16_kernel(const float* __restrict__ CT, const float* __restrict__ W1,
                             const float* __restrict__ B1, const float* __restrict__ W2,
                             float* __restrict__ SIG) {
  int i = blockIdx.x;            // 0..224
  int tid = threadIdx.x;         // 256
  float c0 = CT[i * 2 + 0], c1 = CT[i * 2 + 1];
  float a[16];
  #pragma unroll
  for (int hh = 0; hh < 16; ++hh) a[hh] = 0.f;
  #pragma unroll
  for (int jj = 0; jj < 2; ++jj) {
    int j = tid + jj * 256;
    float h = fmaxf(c0 * W1[j * 2 + 0] + c1 * W1[j * 2 + 1] + B1[j], 0.f);
    #pragma unroll
    for (int hh = 0; hh < 16; ++hh) a[hh] += h * W2[hh * 512 + j];
  }
  __shared__ float red[4][16];
  #pragma unroll
  for (int hh = 0; hh < 16; ++hh) {
    float v = a[hh];
    for (int m = 1; m < 64; m <<= 1) v += __shfl_xor(v, m);
    if ((tid & 63) == 0) red[tid >> 6][hh] = v;
  }
  __syncthreads();
  if (tid < 16) {
    float v = red[0][tid] + red[1][tid] + red[2][tid] + red[3][tid];
    SIG[i * 16 + tid] = 16.f / (1.f + __expf(-v));
  }
}

__global__ void cmb_kernel(const float* __restrict__ SIG, const float* __restrict__ MASK,
                           const int* __restrict__ RPI, float* __restrict__ CMB) {
  int b = blockIdx.x;            // (w,h) = 256 blocks
  int w = b >> 4, h = b & 15;
  int tid = threadIdx.x;
  const float* mrow = &MASK[(size_t)w * 4096];
  float* crow = &CMB[(size_t)b * 4096];
  #pragma unroll
  for (int it = 0; it < 16; ++it) {
    int nm = it * 256 + tid;
    crow[nm] = SIG[RPI[nm] * 16 + h] + mrow[nm];
  }
}

// ============ 128x256 / BK=32 / 8-wave / triple-buffer pipeline ============
// LDS: 3 bufs x (A[128][32] 8KB | B[256][32] 16KB) = 72KB. 2 blocks/CU.
// Per K-tile t (buf t%3), 2 phases:
//  P0: read A frags 0-3 + B frags 0-1; stage B(t+2); bar; lgkm0; 8 MFMA; bar.
//  P1: read B frags 2-3; stage A(t+3); vmcnt(4|3|0); bar; lgkm0; 8 MFMA; bar.
// vmcnt(4) retires A(t+1),B(t+1) (3 phases of load slack). WAR: every staged
// region is >= 1 barrier past its last reader's lgkm drain (triple-buffer rotation).

#define GEMM32_KLOOP()                                                     \
  _Pragma("unroll")                                                        \
  for (int t = 0; t < 16; ++t) {                                           \
    const int Sb = (t % 3) * 12288;                                        \
    _Pragma("unroll")                                                      \
    for (int m = 0; m < 4; ++m)                                            \
      af[m] = *(const bf16x8*)&S[Sb + (wm * 64 + m * 16 + fr) * 32 + fsw]; \
    _Pragma("unroll")                                                      \
    for (int n = 0; n < 2; ++n)                                            \
      bf[n] = *(const bf16x8*)&S[Sb + 4096 + (wn * 64 + n * 16 + fr) * 32 + fsw]; \
    if (t + 2 <= 15) stageB(t + 2);                                        \
    FENCE(); __builtin_amdgcn_s_barrier(); FENCE();                        \
    WAITL0(); __builtin_amdgcn_sched_barrier(0);                           \
    __builtin_amdgcn_s_setprio(1);                                         \
    _Pragma("unroll")                                                      \
    for (int m = 0; m < 4; ++m)                                            \
      _Pragma("unroll")                                                    \
      for (int n = 0; n < 2; ++n)                                          \
        acc[m][n] = mfma16(af[m], bf[n], acc[m][n]);                       \
    __builtin_amdgcn_s_setprio(0);                                         \
    FENCE(); __builtin_amdgcn_s_barrier(); FENCE();                        \
    _Pragma("unroll")                                                      \
    for (int n = 0; n < 2; ++n)                                            \
      bf[n] = *(const bf16x8*)&S[Sb + 4096 + (wn * 64 + (n + 2) * 16 + fr) * 32 + fsw]; \
    if (t + 3 <= 15) stageA(t + 3);                                        \
    if (t <= 12) { WAITV4(); }                                             \
    else if (t == 13) { WAITV3(); }                                        \
    else if (t == 14) { WAITV0(); }                                        \
    FENCE(); __builtin_amdgcn_s_barrier(); FENCE();                        \
    WAITL0(); __builtin_amdgcn_sched_barrier(0);                           \
    __builtin_amdgcn_s_setprio(1);                                         \
    _Pragma("unroll")                                                      \
    for (int m = 0; m < 4; ++m)                                            \
      _Pragma("unroll")                                                    \
      for (int n = 0; n < 2; ++n)                                          \
        acc[m][n + 2] = mfma16(af[m], bf[n], acc[m][n + 2]);               \
    __builtin_amdgcn_s_setprio(0);                                         \
    FENCE(); __builtin_amdgcn_s_barrier(); FENCE();                        \
  }

// ---------------- qkv GEMM: XB bf16 [131072,512] @ WQB^T -> bf16 [131072,1536] ----

__global__ __launch_bounds__(512, 4) void qkv_g32(
    const u16* __restrict__ XB, const u16* __restrict__ WB,
    const float* __restrict__ QB, const float* __restrict__ VB,
    u16* __restrict__ QKV) {
  __shared__ u16 S[36864];  // 3 x (A 4096 + B 8192) u16 = 73728 B
  const int tid = threadIdx.x, lane = tid & 63, w = tid >> 6;
  int bid = blockIdx.x;                           // 6144 = 1024m x 6n
  int swz = (bid & 7) * 768 + (bid >> 3);         // bijective XCD swizzle
  const int mt = swz / 6, nt = swz - mt * 6;
  const long m0 = (long)mt * 128, n0 = (long)nt * 256;
  const int wm = w >> 2, wn = w & 3;              // 2M x 4N waves; wave tile 64x64
  const int fr = lane & 15, lg = lane >> 4;
  const int fsw = (lg ^ (lane & 3)) << 3;         // swizzled chunk (u16 units)
  const f32x4 zf = {0.f, 0.f, 0.f, 0.f};

  f32x4 acc[4][4];
  #pragma unroll
  for (int mi = 0; mi < 4; ++mi)
    #pragma unroll
    for (int ni = 0; ni < 4; ++ni) acc[mi][ni] = zf;

  // staging sources (per-thread constant bases; swizzle (sc ^ row&3) baked in)
  const int arow = tid >> 2;
  const int asc = (tid & 3) ^ (arow & 3);
  const u16* aSrc = &XB[(size_t)(m0 + arow) * 512 + asc * 8];
  const u16* bSrc0 = &WB[(size_t)(n0 + arow) * 512 + asc * 8];          // rows 0-127
  const u16* bSrc1 = &WB[(size_t)(n0 + 128 + arow) * 512 + asc * 8];    // rows 128-255

  auto stageA = [&](int kt) {
    gl_lds16(aSrc + kt * 32, &S[(kt % 3) * 12288 + w * 512]);
  };
  auto stageB = [&](int kt) {
    gl_lds16(bSrc0 + kt * 32, &S[(kt % 3) * 12288 + 4096 + w * 512]);
    gl_lds16(bSrc1 + kt * 32, &S[(kt % 3) * 12288 + 8192 + w * 512]);
  };

  bf16x8 af[4], bf[2];

  // prologue: A0,B0 (tile0), A1,B1, A2 in flight
  stageA(0); stageB(0); stageA(1); stageB(1); stageA(2);
  WAITV4();                                       // A0,B0 resident; A1,B1,A2 in flight
  FENCE(); __builtin_amdgcn_s_barrier(); FENCE();

  GEMM32_KLOOP()

  #pragma unroll
  for (int ni = 0; ni < 4; ++ni) {
    const long c = n0 + wn * 64 + ni * 16 + fr;
    float bias = (c < 512) ? QB[c] : (c < 1024 ? 0.f : VB[c - 1024]);
    #pragma unroll
    for (int mi = 0; mi < 4; ++mi)
      #pragma unroll
      for (int r = 0; r < 4; ++r) {
        long row = m0 + wm * 64 + mi * 16 + lg * 4 + r;
        QKV[row * 1536 + c] = f2bf(acc[mi][ni][r] + bias);
      }
  }
}

// ---------------- proj GEMM: QKV q-cols bf16 [131072,512](lda=1536) @ WPB^T + b -> f32 ----

__global__ __launch_bounds__(512, 4) void proj_g32(
    const u16* __restrict__ A, const u16* __restrict__ WB,
    const float* __restrict__ PB, float* __restrict__ OUT) {
  __shared__ u16 S[36864];
  const int tid = threadIdx.x, lane = tid & 63, w = tid >> 6;
  int bid = blockIdx.x;                           // 2048 = 1024m x 2n
  int swz = (bid & 7) * 256 + (bid >> 3);
  const int mt = swz >> 1, nt = swz & 1;
  const long m0 = (long)mt * 128, n0 = (long)nt * 256;
  const int wm = w >> 2, wn = w & 3;
  const int fr = lane & 15, lg = lane >> 4;
  const int fsw = (lg ^ (lane & 3)) << 3;
  const f32x4 zf = {0.f, 0.f, 0.f, 0.f};

  f32x4 acc[4][4];
  #pragma unroll
  for (int mi = 0; mi < 4; ++mi)
    #pragma unroll
    for (int ni = 0; ni < 4; ++ni) acc[mi][ni] = zf;

  const int arow = tid >> 2;
  const int asc = (tid & 3) ^ (arow & 3);
  const u16* aSrc = &A[(size_t)(m0 + arow) * 1536 + asc * 8];           // lda 1536
  const u16* bSrc0 = &WB[(size_t)(n0 + arow) * 512 + asc * 8];
  const u16* bSrc1 = &WB[(size_t)(n0 + 128 + arow) * 512 + asc * 8];

  auto stageA = [&](int kt) {
    gl_lds16(aSrc + kt * 32, &S[(kt % 3) * 12288 + w * 512]);
  };
  auto stageB = [&](int kt) {
    gl_lds16(bSrc0 + kt * 32, &S[(kt % 3) * 12288 + 4096 + w * 512]);
    gl_lds16(bSrc1 + kt * 32, &S[(kt % 3) * 12288 + 8192 + w * 512]);
  };

  bf16x8 af[4], bf[2];

  stageA(0); stageB(0); stageA(1); stageB(1); stageA(2);
  WAITV4();
  FENCE(); __builtin_amdgcn_s_barrier(); FENCE();

  GEMM32_KLOOP()

  #pragma unroll
  for (int ni = 0; ni < 4; ++ni) {
    const long c = n0 + wn * 64 + ni * 16 + fr;
    float bias = PB[c];
    #pragma unroll
    for (int mi = 0; mi < 4; ++mi)
      #pragma unroll
      for (int r = 0; r < 4; ++r) {
        long row = m0 + wm * 64 + mi * 16 + lg * 4 + r;
        OUT[row * 512 + c] = acc[mi][ni][r] + bias;
      }
  }
}

// ---------------- qkv GEMM fallback (small ws): reg-staged A, 128x128 ----------------

__global__ __launch_bounds__(256, 2) void qkv_gemm_rs(
    const float* __restrict__ X, const u16* __restrict__ WB,
    const float* __restrict__ QB, const float* __restrict__ VB,
    u16* __restrict__ QKV) {
  __shared__ u16 As[128 * 64];
  __shared__ u16 Bs[128 * 64];
  const int tid = threadIdx.x, lane = tid & 63, w = tid >> 6;
  int bid = blockIdx.x;
  int swz = (bid & 7) * 1536 + (bid >> 3);
  const int mt = swz / 12, nt = swz - mt * 12;
  const long m0 = (long)mt * 128, n0 = (long)nt * 128;
  const int wm = w >> 1, wn = w & 1;
  const f32x4 zf = {0.f, 0.f, 0.f, 0.f};

  f32x4 acc[4][4];
  #pragma unroll
  for (int mi = 0; mi < 4; ++mi)
    #pragma unroll
    for (int ni = 0; ni < 4; ++ni) acc[mi][ni] = zf;

  const int fr = lane & 15;
  const int fsw = ((lane >> 4) ^ (lane & 7)) * 8;
  const u16* Ap = &As[(wm * 64 + fr) * 64 + fsw];
  const u16* Bp = &Bs[(wn * 64 + fr) * 64 + fsw];

  for (int t = 0; t < 8; ++t) {
    float4 av[8];
    #pragma unroll
    for (int i = 0; i < 8; ++i) {
      int ch = tid + (i << 8);
      int row = ch >> 4, kc = ch & 15;
      av[i] = *(const float4*)&X[(m0 + row) * 512 + t * 64 + kc * 4];
    }
    #pragma unroll
    for (int i = 0; i < 4; ++i) {
      int ch = ((w << 2) + i) * 64 + lane;
      int row = ch >> 3, kc = (ch & 7) ^ (row & 7);
      gl_lds16(&WB[(n0 + row) * 512 + t * 64 + kc * 8], &Bs[((w << 2) + i) * 512]);
    }
    #pragma unroll
    for (int i = 0; i < 8; ++i) {
      int ch = tid + (i << 8);
      int row = ch >> 4, kc = ch & 15;
      int kcs = kc ^ ((row & 7) << 1);
      us4 u; u.x = f2bf(av[i].x); u.y = f2bf(av[i].y); u.z = f2bf(av[i].z); u.w = f2bf(av[i].w);
      *(us4*)&As[row * 64 + kcs * 4] = u;
    }
    __syncthreads();
    #pragma unroll
    for (int ks = 0; ks < 2; ++ks) {
      bf16x8 af[4], bfr[4];
      #pragma unroll
      for (int mi = 0; mi < 4; ++mi) af[mi] = ldswz(Ap + mi * 1024, ks);
      #pragma unroll
      for (int ni = 0; ni < 4; ++ni) bfr[ni] = ldswz(Bp + ni * 1024, ks);
      #pragma unroll
      for (int mi = 0; mi < 4; ++mi)
        #pragma unroll
        for (int ni = 0; ni < 4; ++ni)
          acc[mi][ni] = mfma16(af[mi], bfr[ni], acc[mi][ni]);
    }
    __syncthreads();
  }

  #pragma unroll
  for (int ni = 0; ni < 4; ++ni) {
    const long c = n0 + wn * 64 + ni * 16 + (lane & 15);
    float bias = (c < 512) ? QB[c] : (c < 1024 ? 0.f : VB[c - 1024]);
    #pragma unroll
    for (int mi = 0; mi < 4; ++mi)
      #pragma unroll
      for (int r = 0; r < 4; ++r) {
        long row = m0 + wm * 64 + mi * 16 + (lane >> 4) * 4 + r;
        QKV[row * 1536 + c] = f2bf(acc[mi][ni][r] + bias);
      }
  }
}

// ---------------- attention: 1 block per window, 4 waves coop per head ----------------

__global__ __launch_bounds__(256, 4) void attn_kernel(
    u16* __restrict__ QKV, const float* __restrict__ CMB, const float* __restrict__ LS) {
  __shared__ u16 sm[7424];       // 14848 B
  u16* qs = sm;                  // [64][40] (aliased by ps)
  u16* ksm = sm + 2560;          // [64][40] (aliased by ps)
  u16* ps = sm;                  // [64][72]
  u16* vt = sm + 5120;           // [32][72] (v transposed: [d][k])
  const int tid = threadIdx.x, lane = tid & 63, w = tid >> 6;
  const int b = blockIdx.x, wi = b & 15;
  const size_t base = (size_t)b * 64 * 1536;
  const int cl = lane & 15, lg = lane >> 4;
  const int srow = tid >> 2, sck = tid & 3;
  const int vd = tid & 31, vkb = tid >> 5;
  const f32x4 zf = {0.f, 0.f, 0.f, 0.f};

  for (int h = 0; h < 16; ++h) {
    const float scale = __expf(fminf(LS[h], 4.6051702f));
    {
      us8 qv = *(const us8*)&QKV[base + (size_t)srow * 1536 + h * 32 + sck * 8];
      float qf[8]; float ss = 0.f;
      #pragma unroll
      for (int j = 0; j < 8; ++j) { qf[j] = bf2f(qv[j]); ss += qf[j] * qf[j]; }
      ss += __shfl_xor(ss, 1); ss += __shfl_xor(ss, 2);
      float rn = scale / fmaxf(sqrtf(ss), 1e-12f);
      us8 qo;
      #pragma unroll
      for (int j = 0; j < 8; ++j) qo[j] = f2bf(qf[j] * rn);
      *(us8*)&qs[srow * 40 + sck * 8] = qo;
    }
    {
      us8 kv = *(const us8*)&QKV[base + (size_t)srow * 1536 + 512 + h * 32 + sck * 8];
      float kf[8]; float ss = 0.f;
      #pragma unroll
      for (int j = 0; j < 8; ++j) { kf[j] = bf2f(kv[j]); ss += kf[j] * kf[j]; }
      ss += __shfl_xor(ss, 1); ss += __shfl_xor(ss, 2);
      float rn = 1.f / fmaxf(sqrtf(ss), 1e-12f);
      us8 ko;
      #pragma unroll
      for (int j = 0; j < 8; ++j) ko[j] = f2bf(kf[j] * rn);
      *(us8*)&ksm[srow * 40 + sck * 8] = ko;
    }
    {
      us8 vo;
      #pragma unroll
      for (int e = 0; e < 8; ++e)
        vo[e] = QKV[base + (size_t)(vkb * 8 + e) * 1536 + 1024 + h * 32 + vd];
      *(us8*)&vt[vd * 72 + vkb * 8] = vo;
    }
    __syncthreads();

    bf16x8 aq = *(const bf16x8*)&qs[(w * 16 + cl) * 40 + lg * 8];
    f32x4 s4[4];
    #pragma unroll
    for (int nt = 0; nt < 4; ++nt) {
      bf16x8 bk = *(const bf16x8*)&ksm[(nt * 16 + cl) * 40 + lg * 8];
      s4[nt] = mfma16(aq, bk, zf);
    }

    const float* cp = &CMB[((size_t)(wi * 16 + h)) << 12];
    const int r0 = w * 16 + lg * 4;
    float p[4][4];
    #pragma unroll
    for (int r = 0; r < 4; ++r) {
      float mx = -3.0e38f;
      #pragma unroll
      for (int q4 = 0; q4 < 4; ++q4) {
        float v = s4[q4][r] + cp[(r0 + r) * 64 + q4 * 16 + cl];
        p[q4][r] = v; mx = fmaxf(mx, v);
      }
      mx = fmaxf(mx, __shfl_xor(mx, 1));
      mx = fmaxf(mx, __shfl_xor(mx, 2));
      mx = fmaxf(mx, __shfl_xor(mx, 4));
      mx = fmaxf(mx, __shfl_xor(mx, 8));
      float sum = 0.f;
      #pragma unroll
      for (int q4 = 0; q4 < 4; ++q4) { float e = __expf(p[q4][r] - mx); p[q4][r] = e; sum += e; }
      sum += __shfl_xor(sum, 1); sum += __shfl_xor(sum, 2);
      sum += __shfl_xor(sum, 4); sum += __shfl_xor(sum, 8);
      float inv = 1.f / sum;
      #pragma unroll
      for (int q4 = 0; q4 < 4; ++q4) p[q4][r] *= inv;
    }
    __syncthreads();

    #pragma unroll
    for (int r = 0; r < 4; ++r)
      #pragma unroll
      for (int q4 = 0; q4 < 4; ++q4)
        ps[(r0 + r) * 72 + q4 * 16 + cl] = f2bf(p[q4][r]);

    f32x4 o4[2]; o4[0] = zf; o4[1] = zf;
    #pragma unroll
    for (int ks = 0; ks < 2; ++ks) {
      bf16x8 ap = *(const bf16x8*)&ps[(w * 16 + cl) * 72 + ks * 32 + lg * 8];
      #pragma unroll
      for (int n2 = 0; n2 < 2; ++n2) {
        bf16x8 bv = *(const bf16x8*)&vt[(n2 * 16 + cl) * 72 + ks * 32 + lg * 8];
        o4[n2] = mfma16(ap, bv, o4[n2]);
      }
    }
    #pragma unroll
    for (int n2 = 0; n2 < 2; ++n2)
      #pragma unroll
      for (int r = 0; r < 4; ++r)
        QKV[base + (size_t)(w * 16 + lg * 4 + r) * 1536 + h * 32 + n2 * 16 + cl] = f2bf(o4[n2][r]);
    __syncthreads();
  }
}

// ---------------- launch ----------------

extern "C" void kernel_launch(void* const* d_in, const int* in_sizes, int n_in,
                              void* d_out, int out_size, void* d_ws, size_t ws_size,
                              hipStream_t stream) {
  const float* X    = (const float*)d_in[0];
  const float* MASK = (const float*)d_in[1];
  const float* QW   = (const float*)d_in[2];
  const float* QB   = (const float*)d_in[3];
  const float* VB   = (const float*)d_in[4];
  const float* LS   = (const float*)d_in[5];
  const float* CW1  = (const float*)d_in[6];
  const float* CB1  = (const float*)d_in[7];
  const float* CW2  = (const float*)d_in[8];
  const float* PW   = (const float*)d_in[9];
  const float* PB   = (const float*)d_in[10];
  const float* CT   = (const float*)d_in[11];
  const int*   RPI  = (const int*)d_in[12];
  float* OUT = (float*)d_out;

  char* ws = (char*)d_ws;
  const bool big = ws_size >= 543178752ull;
  u16* QKV = (u16*)ws;                                    // 402,653,184 B
  u16* XB  = (u16*)(ws + 402653184ull);                   // 134,217,728 B (big only)
  size_t off = big ? 536870912ull : 402653184ull;
  float* CMB = (float*)(ws + off);  off += 4194304ull;    // 4 MB
  float* SIG = (float*)(ws + off);  off += 16384ull;
  u16*   WQB = (u16*)(ws + off);    off += 1572864ull;
  u16*   WPB = (u16*)(ws + off);

  conv_w_kernel<<<1024, 256, 0, stream>>>(QW, PW, WQB, WPB);
  sig16_kernel<<<225, 256, 0, stream>>>(CT, CW1, CB1, CW2, SIG);
  cmb_kernel<<<256, 256, 0, stream>>>(SIG, MASK, RPI, CMB);
  if (big) {
    xconv_kernel<<<32768, 256, 0, stream>>>(X, XB);
    qkv_g32<<<6144, 512, 0, stream>>>(XB, WQB, QB, VB, QKV);
  } else {
    qkv_gemm_rs<<<12288, 256, 0, stream>>>(X, WQB, QB, VB, QKV);
  }
  attn_kernel<<<2048, 256, 0, stream>>>(QKV, CMB, LS);
  proj_g32<<<2048, 512, 0, stream>>>(QKV, WPB, PB, OUT);
}

// Round 9
// 641.941 us; speedup vs baseline: 1.5629x; 1.0603x over previous
//
#include <hip/hip_runtime.h>
#include <stdint.h>
#include <stddef.h>

// SwinV2-B stage-3 window attention, MI355X bf16-MFMA pipeline.
// Round 9: fix BK=32 LDS swizzle (chunk ^= (row>>1)&3, 2-way free) and
// LDS-staged full-line bf16 epilogue in qkv (kills partial-line write thrash).
// Big ws layout (ws_size >= 543,178,752 B):
//   [0)            QKV bf16 [131072][1536]
//   [402653184)    XB  bf16 [131072][512]
//   [536870912)    CMB f32 [16w][16h][64][64]
//   [541065216)    SIG f32 [225][16] (pad 16K)
//   [541081600)    WQB bf16 [1536][512]
//   [542654464)    WPB bf16 [512][512]

typedef __attribute__((ext_vector_type(8))) short bf16x8;
typedef __attribute__((ext_vector_type(4))) float f32x4;
typedef __attribute__((ext_vector_type(4))) unsigned short us4;
typedef __attribute__((ext_vector_type(8))) unsigned short us8;
typedef unsigned short u16;
typedef unsigned int u32;

#define FENCE() asm volatile("" ::: "memory")
#define WAITV4() asm volatile("s_waitcnt vmcnt(4)" ::: "memory")
#define WAITV3() asm volatile("s_waitcnt vmcnt(3)" ::: "memory")
#define WAITV0() asm volatile("s_waitcnt vmcnt(0)" ::: "memory")
#define WAITL0() asm volatile("s_waitcnt lgkmcnt(0)" ::: "memory")

__device__ __forceinline__ u16 f2bf(float f) {
  union { __bf16 b; u16 u; } cv;
  cv.b = (__bf16)f;            // hardware RNE convert on gfx950
  return cv.u;
}
__device__ __forceinline__ float bf2f(u16 s) {
  return __uint_as_float(((u32)s) << 16);
}
__device__ __forceinline__ void gl_lds16(const void* g, void* l) {
  __builtin_amdgcn_global_load_lds(
      (const __attribute__((address_space(1))) u32*)g,
      (__attribute__((address_space(3))) u32*)l, 16, 0, 0);
}
__device__ __forceinline__ f32x4 mfma16(bf16x8 a, bf16x8 b, f32x4 c) {
  return __builtin_amdgcn_mfma_f32_16x16x32_bf16(a, b, c, 0, 0, 0);
}
__device__ __forceinline__ bf16x8 ldswz(const u16* p, int ks) {
  return *(const bf16x8*)((const u16*)((uintptr_t)p ^ (uintptr_t)(ks << 6)));
}

// ---------------- prep kernels ----------------

__global__ void conv_w_kernel(const float* __restrict__ QW, const float* __restrict__ PW,
                              u16* __restrict__ WQB, u16* __restrict__ WPB) {
  int idx = blockIdx.x * 256 + threadIdx.x;   // 262144 float4 chunks total
  const int NQ = 1536 * 512 / 4;              // 196608
  float4 v; u16* dst;
  if (idx < NQ) { v = ((const float4*)QW)[idx]; dst = WQB + (size_t)idx * 4; }
  else { int k = idx - NQ; v = ((const float4*)PW)[k]; dst = WPB + (size_t)k * 4; }
  us4 u; u.x = f2bf(v.x); u.y = f2bf(v.y); u.z = f2bf(v.z); u.w = f2bf(v.w);
  *(us4*)dst = u;
}

__global__ void xconv_kernel(const float* __restrict__ X, u16* __restrict__ XB) {
  size_t idx = (size_t)blockIdx.x * 256 + threadIdx.x;   // 8,388,608 threads, 8 f32 each
  float4 a = ((const float4*)X)[idx * 2];
  float4 b = ((const float4*)X)[idx * 2 + 1];
  us8 o;
  o[0] = f2bf(a.x); o[1] = f2bf(a.y); o[2] = f2bf(a.z); o[3] = f2bf(a.w);
  o[4] = f2bf(b.x); o[5] = f2bf(b.y); o[6] = f2bf(b.z); o[7] = f2bf(b.w);
  *(us8*)&XB[idx * 8] = o;
}

__global__ void sig16_kernel(const float* __restrict__ CT, const float* __restrict__ W1,
                             const float* __restrict__ B1, const float* __restrict__ W2,
                             float* __restrict__ SIG) {
  int i = blockIdx.x;            // 0..224
  int tid = threadIdx.x;         // 256
  float c0 = CT[i * 2 + 0], c1 = CT[i * 2 + 1];
  float a[16];
  #pragma unroll
  for (int hh = 0; hh < 16; ++hh) a[hh] = 0.f;
  #pragma unroll
  for (int jj = 0; jj < 2; ++jj) {
    int j = tid + jj * 256;
    float h = fmaxf(c0 * W1[j * 2 + 0] + c1 * W1[j * 2 + 1] + B1[j], 0.f);
    #pragma unroll
    for (int hh = 0; hh < 16; ++hh) a[hh] += h * W2[hh * 512 + j];
  }
  __shared__ float red[4][16];
  #pragma unroll
  for (int hh = 0; hh < 16; ++hh) {
    float v = a[hh];
    for (int m = 1; m < 64; m <<= 1) v += __shfl_xor(v, m);
    if ((tid & 63) == 0) red[tid >> 6][hh] = v;
  }
  __syncthreads();
  if (tid < 16) {
    float v = red[0][tid] + red[1][tid] + red[2][tid] + red[3][tid];
    SIG[i * 16 + tid] = 16.f / (1.f + __expf(-v));
  }
}

__global__ void cmb_kernel(const float* __restrict__ SIG, const float* __restrict__ MASK,
                           const int* __restrict__ RPI, float* __restrict__ CMB) {
  int b = blockIdx.x;            // (w,h) = 256 blocks
  int w = b >> 4, h = b & 15;
  int tid = threadIdx.x;
  const float* mrow = &MASK[(size_t)w * 4096];
  float* crow = &CMB[(size_t)b * 4096];
  #pragma unroll
  for (int it = 0; it < 16; ++it) {
    int nm = it * 256 + tid;
    crow[nm] = SIG[RPI[nm] * 16 + h] + mrow[nm];
  }
}

// ============ 128x256 / BK=32 / 8-wave / triple-buffer pipeline ============
// LDS: 3 bufs x (A[128][32] 8KB | B[256][32] 16KB) = 72KB. 2 blocks/CU.
// Swizzle: 16B chunk index ^= (row>>1)&3 on BOTH stage-source and read
// (64B rows: gives 8 bank-quads x 2 lanes = 2-way = free).
// Per K-tile t (buf t%3), 2 phases:
//  P0: read A frags 0-3 + B frags 0-1; stage B(t+2); bar; lgkm0; 8 MFMA; bar.
//  P1: read B frags 2-3; stage A(t+3); vmcnt(4|3|0); bar; lgkm0; 8 MFMA; bar.

#define GEMM32_KLOOP()                                                     \
  _Pragma("unroll")                                                        \
  for (int t = 0; t < 16; ++t) {                                           \
    const int Sb = (t % 3) * 12288;                                        \
    _Pragma("unroll")                                                      \
    for (int m = 0; m < 4; ++m)                                            \
      af[m] = *(const bf16x8*)&S[Sb + (wm * 64 + m * 16 + fr) * 32 + fsw]; \
    _Pragma("unroll")                                                      \
    for (int n = 0; n < 2; ++n)                                            \
      bf[n] = *(const bf16x8*)&S[Sb + 4096 + (wn * 64 + n * 16 + fr) * 32 + fsw]; \
    if (t + 2 <= 15) stageB(t + 2);                                        \
    FENCE(); __builtin_amdgcn_s_barrier(); FENCE();                        \
    WAITL0(); __builtin_amdgcn_sched_barrier(0);                           \
    __builtin_amdgcn_s_setprio(1);                                         \
    _Pragma("unroll")                                                      \
    for (int m = 0; m < 4; ++m)                                            \
      _Pragma("unroll")                                                    \
      for (int n = 0; n < 2; ++n)                                          \
        acc[m][n] = mfma16(af[m], bf[n], acc[m][n]);                       \
    __builtin_amdgcn_s_setprio(0);                                         \
    FENCE(); __builtin_amdgcn_s_barrier(); FENCE();                        \
    _Pragma("unroll")                                                      \
    for (int n = 0; n < 2; ++n)                                            \
      bf[n] = *(const bf16x8*)&S[Sb + 4096 + (wn * 64 + (n + 2) * 16 + fr) * 32 + fsw]; \
    if (t + 3 <= 15) stageA(t + 3);                                        \
    if (t <= 12) { WAITV4(); }                                             \
    else if (t == 13) { WAITV3(); }                                        \
    else if (t == 14) { WAITV0(); }                                        \
    FENCE(); __builtin_amdgcn_s_barrier(); FENCE();                        \
    WAITL0(); __builtin_amdgcn_sched_barrier(0);                           \
    __builtin_amdgcn_s_setprio(1);                                         \
    _Pragma("unroll")                                                      \
    for (int m = 0; m < 4; ++m)                                            \
      _Pragma("unroll")                                                    \
      for (int n = 0; n < 2; ++n)                                          \
        acc[m][n + 2] = mfma16(af[m], bf[n], acc[m][n + 2]);               \
    __builtin_amdgcn_s_setprio(0);                                         \
    FENCE(); __builtin_amdgcn_s_barrier(); FENCE();                        \
  }

// ---------------- qkv GEMM: XB bf16 [131072,512] @ WQB^T -> bf16 [131072,1536] ----

__global__ __launch_bounds__(512, 4) void qkv_g32(
    const u16* __restrict__ XB, const u16* __restrict__ WB,
    const float* __restrict__ QB, const float* __restrict__ VB,
    u16* __restrict__ QKV) {
  __shared__ u16 S[36864];  // 3 x (A 4096 + B 8192) u16 = 73728 B
  const int tid = threadIdx.x, lane = tid & 63, w = tid >> 6;
  int bid = blockIdx.x;                           // 6144 = 1024m x 6n
  int swz = (bid & 7) * 768 + (bid >> 3);         // bijective XCD swizzle
  const int mt = swz / 6, nt = swz - mt * 6;
  const long m0 = (long)mt * 128, n0 = (long)nt * 256;
  const int wm = w >> 2, wn = w & 3;              // 2M x 4N waves; wave tile 64x64
  const int fr = lane & 15, lg = lane >> 4;
  const int fsw = (lg ^ ((fr >> 1) & 3)) << 3;    // swizzled chunk (u16 units)
  const f32x4 zf = {0.f, 0.f, 0.f, 0.f};

  f32x4 acc[4][4];
  #pragma unroll
  for (int mi = 0; mi < 4; ++mi)
    #pragma unroll
    for (int ni = 0; ni < 4; ++ni) acc[mi][ni] = zf;

  // staging sources (per-thread constant bases; swizzle (sc ^ (row>>1)&3) baked in)
  const int arow = tid >> 2;
  const int asc = (tid & 3) ^ ((arow >> 1) & 3);
  const u16* aSrc = &XB[(size_t)(m0 + arow) * 512 + asc * 8];
  const u16* bSrc0 = &WB[(size_t)(n0 + arow) * 512 + asc * 8];          // rows 0-127
  const u16* bSrc1 = &WB[(size_t)(n0 + 128 + arow) * 512 + asc * 8];    // rows 128-255

  auto stageA = [&](int kt) {
    gl_lds16(aSrc + kt * 32, &S[(kt % 3) * 12288 + w * 512]);
  };
  auto stageB = [&](int kt) {
    gl_lds16(bSrc0 + kt * 32, &S[(kt % 3) * 12288 + 4096 + w * 512]);
    gl_lds16(bSrc1 + kt * 32, &S[(kt % 3) * 12288 + 8192 + w * 512]);
  };

  bf16x8 af[4], bf[2];

  // prologue: A0,B0 (tile0), A1,B1, A2 in flight
  stageA(0); stageB(0); stageA(1); stageB(1); stageA(2);
  WAITV4();                                       // A0,B0 resident; A1,B1,A2 in flight
  FENCE(); __builtin_amdgcn_s_barrier(); FENCE();

  GEMM32_KLOOP()

  // LDS-staged epilogue: per-wave [64][72] bf16 tile, then full-line us8 stores.
  // Safe: final trailing barrier above means every wave's LDS reads drained.
  u16* eb = &S[w * 4608];   // 64*72 u16 = 9216 B per wave; 8 waves = 73728 B
  #pragma unroll
  for (int ni = 0; ni < 4; ++ni) {
    const long c = n0 + wn * 64 + ni * 16 + fr;
    float bias = (c < 512) ? QB[c] : (c < 1024 ? 0.f : VB[c - 1024]);
    #pragma unroll
    for (int mi = 0; mi < 4; ++mi)
      #pragma unroll
      for (int r = 0; r < 4; ++r)
        eb[(mi * 16 + lg * 4 + r) * 72 + ni * 16 + fr] = f2bf(acc[mi][ni][r] + bias);
  }
  WAITL0();
  #pragma unroll
  for (int i = 0; i < 8; ++i) {
    int row = i * 8 + (lane >> 3);
    int c16 = lane & 7;
    us8 v = *(const us8*)&eb[row * 72 + c16 * 8];
    *(us8*)&QKV[(size_t)(m0 + wm * 64 + row) * 1536 + n0 + wn * 64 + c16 * 8] = v;
  }
}

// ---------------- proj GEMM: QKV q-cols bf16 [131072,512](lda=1536) @ WPB^T + b -> f32 ----

__global__ __launch_bounds__(512, 4) void proj_g32(
    const u16* __restrict__ A, const u16* __restrict__ WB,
    const float* __restrict__ PB, float* __restrict__ OUT) {
  __shared__ u16 S[36864];
  const int tid = threadIdx.x, lane = tid & 63, w = tid >> 6;
  int bid = blockIdx.x;                           // 2048 = 1024m x 2n
  int swz = (bid & 7) * 256 + (bid >> 3);
  const int mt = swz >> 1, nt = swz & 1;
  const long m0 = (long)mt * 128, n0 = (long)nt * 256;
  const int wm = w >> 2, wn = w & 3;
  const int fr = lane & 15, lg = lane >> 4;
  const int fsw = (lg ^ ((fr >> 1) & 3)) << 3;
  const f32x4 zf = {0.f, 0.f, 0.f, 0.f};

  f32x4 acc[4][4];
  #pragma unroll
  for (int mi = 0; mi < 4; ++mi)
    #pragma unroll
    for (int ni = 0; ni < 4; ++ni) acc[mi][ni] = zf;

  const int arow = tid >> 2;
  const int asc = (tid & 3) ^ ((arow >> 1) & 3);
  const u16* aSrc = &A[(size_t)(m0 + arow) * 1536 + asc * 8];           // lda 1536
  const u16* bSrc0 = &WB[(size_t)(n0 + arow) * 512 + asc * 8];
  const u16* bSrc1 = &WB[(size_t)(n0 + 128 + arow) * 512 + asc * 8];

  auto stageA = [&](int kt) {
    gl_lds16(aSrc + kt * 32, &S[(kt % 3) * 12288 + w * 512]);
  };
  auto stageB = [&](int kt) {
    gl_lds16(bSrc0 + kt * 32, &S[(kt % 3) * 12288 + 4096 + w * 512]);
    gl_lds16(bSrc1 + kt * 32, &S[(kt % 3) * 12288 + 8192 + w * 512]);
  };

  bf16x8 af[4], bf[2];

  stageA(0); stageB(0); stageA(1); stageB(1); stageA(2);
  WAITV4();
  FENCE(); __builtin_amdgcn_s_barrier(); FENCE();

  GEMM32_KLOOP()

  #pragma unroll
  for (int ni = 0; ni < 4; ++ni) {
    const long c = n0 + wn * 64 + ni * 16 + fr;
    float bias = PB[c];
    #pragma unroll
    for (int mi = 0; mi < 4; ++mi)
      #pragma unroll
      for (int r = 0; r < 4; ++r) {
        long row = m0 + wm * 64 + mi * 16 + lg * 4 + r;
        OUT[row * 512 + c] = acc[mi][ni][r] + bias;
      }
  }
}

// ---------------- qkv GEMM fallback (small ws): reg-staged A, 128x128 ----------------

__global__ __launch_bounds__(256, 2) void qkv_gemm_rs(
    const float* __restrict__ X, const u16* __restrict__ WB,
    const float* __restrict__ QB, const float* __restrict__ VB,
    u16* __restrict__ QKV) {
  __shared__ u16 As[128 * 64];
  __shared__ u16 Bs[128 * 64];
  const int tid = threadIdx.x, lane = tid & 63, w = tid >> 6;
  int bid = blockIdx.x;
  int swz = (bid & 7) * 1536 + (bid >> 3);
  const int mt = swz / 12, nt = swz - mt * 12;
  const long m0 = (long)mt * 128, n0 = (long)nt * 128;
  const int wm = w >> 1, wn = w & 1;
  const f32x4 zf = {0.f, 0.f, 0.f, 0.f};

  f32x4 acc[4][4];
  #pragma unroll
  for (int mi = 0; mi < 4; ++mi)
    #pragma unroll
    for (int ni = 0; ni < 4; ++ni) acc[mi][ni] = zf;

  const int fr = lane & 15;
  const int fsw = ((lane >> 4) ^ (lane & 7)) * 8;
  const u16* Ap = &As[(wm * 64 + fr) * 64 + fsw];
  const u16* Bp = &Bs[(wn * 64 + fr) * 64 + fsw];

  for (int t = 0; t < 8; ++t) {
    float4 av[8];
    #pragma unroll
    for (int i = 0; i < 8; ++i) {
      int ch = tid + (i << 8);
      int row = ch >> 4, kc = ch & 15;
      av[i] = *(const float4*)&X[(m0 + row) * 512 + t * 64 + kc * 4];
    }
    #pragma unroll
    for (int i = 0; i < 4; ++i) {
      int ch = ((w << 2) + i) * 64 + lane;
      int row = ch >> 3, kc = (ch & 7) ^ (row & 7);
      gl_lds16(&WB[(n0 + row) * 512 + t * 64 + kc * 8], &Bs[((w << 2) + i) * 512]);
    }
    #pragma unroll
    for (int i = 0; i < 8; ++i) {
      int ch = tid + (i << 8);
      int row = ch >> 4, kc = ch & 15;
      int kcs = kc ^ ((row & 7) << 1);
      us4 u; u.x = f2bf(av[i].x); u.y = f2bf(av[i].y); u.z = f2bf(av[i].z); u.w = f2bf(av[i].w);
      *(us4*)&As[row * 64 + kcs * 4] = u;
    }
    __syncthreads();
    #pragma unroll
    for (int ks = 0; ks < 2; ++ks) {
      bf16x8 af[4], bfr[4];
      #pragma unroll
      for (int mi = 0; mi < 4; ++mi) af[mi] = ldswz(Ap + mi * 1024, ks);
      #pragma unroll
      for (int ni = 0; ni < 4; ++ni) bfr[ni] = ldswz(Bp + ni * 1024, ks);
      #pragma unroll
      for (int mi = 0; mi < 4; ++mi)
        #pragma unroll
        for (int ni = 0; ni < 4; ++ni)
          acc[mi][ni] = mfma16(af[mi], bfr[ni], acc[mi][ni]);
    }
    __syncthreads();
  }

  #pragma unroll
  for (int ni = 0; ni < 4; ++ni) {
    const long c = n0 + wn * 64 + ni * 16 + (lane & 15);
    float bias = (c < 512) ? QB[c] : (c < 1024 ? 0.f : VB[c - 1024]);
    #pragma unroll
    for (int mi = 0; mi < 4; ++mi)
      #pragma unroll
      for (int r = 0; r < 4; ++r) {
        long row = m0 + wm * 64 + mi * 16 + (lane >> 4) * 4 + r;
        QKV[row * 1536 + c] = f2bf(acc[mi][ni][r] + bias);
      }
  }
}

// ---------------- attention: 1 block per window, 4 waves coop per head ----------------

__global__ __launch_bounds__(256, 4) void attn_kernel(
    u16* __restrict__ QKV, const float* __restrict__ CMB, const float* __restrict__ LS) {
  __shared__ u16 sm[7424];       // 14848 B
  u16* qs = sm;                  // [64][40] (aliased by ps)
  u16* ksm = sm + 2560;          // [64][40] (aliased by ps)
  u16* ps = sm;                  // [64][72]
  u16* vt = sm + 5120;           // [32][72] (v transposed: [d][k])
  const int tid = threadIdx.x, lane = tid & 63, w = tid >> 6;
  const int b = blockIdx.x, wi = b & 15;
  const size_t base = (size_t)b * 64 * 1536;
  const int cl = lane & 15, lg = lane >> 4;
  const int srow = tid >> 2, sck = tid & 3;
  const int vd = tid & 31, vkb = tid >> 5;
  const f32x4 zf = {0.f, 0.f, 0.f, 0.f};

  for (int h = 0; h < 16; ++h) {
    const float scale = __expf(fminf(LS[h], 4.6051702f));
    {
      us8 qv = *(const us8*)&QKV[base + (size_t)srow * 1536 + h * 32 + sck * 8];
      float qf[8]; float ss = 0.f;
      #pragma unroll
      for (int j = 0; j < 8; ++j) { qf[j] = bf2f(qv[j]); ss += qf[j] * qf[j]; }
      ss += __shfl_xor(ss, 1); ss += __shfl_xor(ss, 2);
      float rn = scale / fmaxf(sqrtf(ss), 1e-12f);
      us8 qo;
      #pragma unroll
      for (int j = 0; j < 8; ++j) qo[j] = f2bf(qf[j] * rn);
      *(us8*)&qs[srow * 40 + sck * 8] = qo;
    }
    {
      us8 kv = *(const us8*)&QKV[base + (size_t)srow * 1536 + 512 + h * 32 + sck * 8];
      float kf[8]; float ss = 0.f;
      #pragma unroll
      for (int j = 0; j < 8; ++j) { kf[j] = bf2f(kv[j]); ss += kf[j] * kf[j]; }
      ss += __shfl_xor(ss, 1); ss += __shfl_xor(ss, 2);
      float rn = 1.f / fmaxf(sqrtf(ss), 1e-12f);
      us8 ko;
      #pragma unroll
      for (int j = 0; j < 8; ++j) ko[j] = f2bf(kf[j] * rn);
      *(us8*)&ksm[srow * 40 + sck * 8] = ko;
    }
    {
      us8 vo;
      #pragma unroll
      for (int e = 0; e < 8; ++e)
        vo[e] = QKV[base + (size_t)(vkb * 8 + e) * 1536 + 1024 + h * 32 + vd];
      *(us8*)&vt[vd * 72 + vkb * 8] = vo;
    }
    __syncthreads();

    bf16x8 aq = *(const bf16x8*)&qs[(w * 16 + cl) * 40 + lg * 8];
    f32x4 s4[4];
    #pragma unroll
    for (int nt = 0; nt < 4; ++nt) {
      bf16x8 bk = *(const bf16x8*)&ksm[(nt * 16 + cl) * 40 + lg * 8];
      s4[nt] = mfma16(aq, bk, zf);
    }

    const float* cp = &CMB[((size_t)(wi * 16 + h)) << 12];
    const int r0 = w * 16 + lg * 4;
    float p[4][4];
    #pragma unroll
    for (int r = 0; r < 4; ++r) {
      float mx = -3.0e38f;
      #pragma unroll
      for (int q4 = 0; q4 < 4; ++q4) {
        float v = s4[q4][r] + cp[(r0 + r) * 64 + q4 * 16 + cl];
        p[q4][r] = v; mx = fmaxf(mx, v);
      }
      mx = fmaxf(mx, __shfl_xor(mx, 1));
      mx = fmaxf(mx, __shfl_xor(mx, 2));
      mx = fmaxf(mx, __shfl_xor(mx, 4));
      mx = fmaxf(mx, __shfl_xor(mx, 8));
      float sum = 0.f;
      #pragma unroll
      for (int q4 = 0; q4 < 4; ++q4) { float e = __expf(p[q4][r] - mx); p[q4][r] = e; sum += e; }
      sum += __shfl_xor(sum, 1); sum += __shfl_xor(sum, 2);
      sum += __shfl_xor(sum, 4); sum += __shfl_xor(sum, 8);
      float inv = 1.f / sum;
      #pragma unroll
      for (int q4 = 0; q4 < 4; ++q4) p[q4][r] *= inv;
    }
    __syncthreads();

    #pragma unroll
    for (int r = 0; r < 4; ++r)
      #pragma unroll
      for (int q4 = 0; q4 < 4; ++q4)
        ps[(r0 + r) * 72 + q4 * 16 + cl] = f2bf(p[q4][r]);

    f32x4 o4[2]; o4[0] = zf; o4[1] = zf;
    #pragma unroll
    for (int ks = 0; ks < 2; ++ks) {
      bf16x8 ap = *(const bf16x8*)&ps[(w * 16 + cl) * 72 + ks * 32 + lg * 8];
      #pragma unroll
      for (int n2 = 0; n2 < 2; ++n2) {
        bf16x8 bv = *(const bf16x8*)&vt[(n2 * 16 + cl) * 72 + ks * 32 + lg * 8];
        o4[n2] = mfma16(ap, bv, o4[n2]);
      }
    }
    #pragma unroll
    for (int n2 = 0; n2 < 2; ++n2)
      #pragma unroll
      for (int r = 0; r < 4; ++r)
        QKV[base + (size_t)(w * 16 + lg * 4 + r) * 1536 + h * 32 + n2 * 16 + cl] = f2bf(o4[n2][r]);
    __syncthreads();
  }
}

// ---------------- launch ----------------

extern "C" void kernel_launch(void* const* d_in, const int* in_sizes, int n_in,
                              void* d_out, int out_size, void* d_ws, size_t ws_size,
                              hipStream_t stream) {
  const float* X    = (const float*)d_in[0];
  const float* MASK = (const float*)d_in[1];
  const float* QW   = (const float*)d_in[2];
  const float* QB   = (const float*)d_in[3];
  const float* VB   = (const float*)d_in[4];
  const float* LS   = (const float*)d_in[5];
  const float* CW1  = (const float*)d_in[6];
  const float* CB1  = (const float*)d_in[7];
  const float* CW2  = (const float*)d_in[8];
  const float* PW   = (const float*)d_in[9];
  const float* PB   = (const float*)d_in[10];
  const float* CT   = (const float*)d_in[11];
  const int*   RPI  = (const int*)d_in[12];
  float* OUT = (float*)d_out;

  char* ws = (char*)d_ws;
  const bool big = ws_size >= 543178752ull;
  u16* QKV = (u16*)ws;                                    // 402,653,184 B
  u16* XB  = (u16*)(ws + 402653184ull);                   // 134,217,728 B (big only)
  size_t off = big ? 536870912ull : 402653184ull;
  float* CMB = (float*)(ws + off);  off += 4194304ull;    // 4 MB
  float* SIG = (float*)(ws + off);  off += 16384ull;
  u16*   WQB = (u16*)(ws + off);    off += 1572864ull;
  u16*   WPB = (u16*)(ws + off);

  conv_w_kernel<<<1024, 256, 0, stream>>>(QW, PW, WQB, WPB);
  sig16_kernel<<<225, 256, 0, stream>>>(CT, CW1, CB1, CW2, SIG);
  cmb_kernel<<<256, 256, 0, stream>>>(SIG, MASK, RPI, CMB);
  if (big) {
    xconv_kernel<<<32768, 256, 0, stream>>>(X, XB);
    qkv_g32<<<6144, 512, 0, stream>>>(XB, WQB, QB, VB, QKV);
  } else {
    qkv_gemm_rs<<<12288, 256, 0, stream>>>(X, WQB, QB, VB, QKV);
  }
  attn_kernel<<<2048, 256, 0, stream>>>(QKV, CMB, LS);
  proj_g32<<<2048, 512, 0, stream>>>(QKV, WPB, PB, OUT);
}

// Round 10
// 641.677 us; speedup vs baseline: 1.5635x; 1.0004x over previous
//
#include <hip/hip_runtime.h>
#include <stdint.h>
#include <stddef.h>

// SwinV2-B stage-3 window attention, MI355X bf16-MFMA pipeline.
// Round 10: barrier-free attention — one (window, head) per wave; Q/K direct
// to register fragments (norm via shfl_xor 16/32); bias+mask as MFMA C-input;
// wave-private LDS only for P-transpose and V^T. qkv/proj/xconv = round 9.
// Big ws layout (ws_size >= 543,178,752 B):
//   [0)            QKV bf16 [131072][1536]
//   [402653184)    XB  bf16 [131072][512]
//   [536870912)    CMB f32 [16w][16h][64][64]
//   [541065216)    SIG f32 [225][16] (pad 16K)
//   [541081600)    WQB bf16 [1536][512]
//   [542654464)    WPB bf16 [512][512]

typedef __attribute__((ext_vector_type(8))) short bf16x8;
typedef __attribute__((ext_vector_type(4))) float f32x4;
typedef __attribute__((ext_vector_type(4))) unsigned short us4;
typedef __attribute__((ext_vector_type(8))) unsigned short us8;
typedef unsigned short u16;
typedef unsigned int u32;

#define FENCE() asm volatile("" ::: "memory")
#define WAITV4() asm volatile("s_waitcnt vmcnt(4)" ::: "memory")
#define WAITV3() asm volatile("s_waitcnt vmcnt(3)" ::: "memory")
#define WAITV0() asm volatile("s_waitcnt vmcnt(0)" ::: "memory")
#define WAITL0() asm volatile("s_waitcnt lgkmcnt(0)" ::: "memory")

__device__ __forceinline__ u16 f2bf(float f) {
  union { __bf16 b; u16 u; } cv;
  cv.b = (__bf16)f;            // hardware RNE convert on gfx950
  return cv.u;
}
__device__ __forceinline__ float bf2f(u16 s) {
  return __uint_as_float(((u32)s) << 16);
}
__device__ __forceinline__ void gl_lds16(const void* g, void* l) {
  __builtin_amdgcn_global_load_lds(
      (const __attribute__((address_space(1))) u32*)g,
      (__attribute__((address_space(3))) u32*)l, 16, 0, 0);
}
__device__ __forceinline__ f32x4 mfma16(bf16x8 a, bf16x8 b, f32x4 c) {
  return __builtin_amdgcn_mfma_f32_16x16x32_bf16(a, b, c, 0, 0, 0);
}
__device__ __forceinline__ bf16x8 ldswz(const u16* p, int ks) {
  return *(const bf16x8*)((const u16*)((uintptr_t)p ^ (uintptr_t)(ks << 6)));
}

// ---------------- prep kernels ----------------

__global__ void conv_w_kernel(const float* __restrict__ QW, const float* __restrict__ PW,
                              u16* __restrict__ WQB, u16* __restrict__ WPB) {
  int idx = blockIdx.x * 256 + threadIdx.x;   // 262144 float4 chunks total
  const int NQ = 1536 * 512 / 4;              // 196608
  float4 v; u16* dst;
  if (idx < NQ) { v = ((const float4*)QW)[idx]; dst = WQB + (size_t)idx * 4; }
  else { int k = idx - NQ; v = ((const float4*)PW)[k]; dst = WPB + (size_t)k * 4; }
  us4 u; u.x = f2bf(v.x); u.y = f2bf(v.y); u.z = f2bf(v.z); u.w = f2bf(v.w);
  *(us4*)dst = u;
}

__global__ void xconv_kernel(const float* __restrict__ X, u16* __restrict__ XB) {
  size_t idx = (size_t)blockIdx.x * 256 + threadIdx.x;   // 8,388,608 threads, 8 f32 each
  float4 a = ((const float4*)X)[idx * 2];
  float4 b = ((const float4*)X)[idx * 2 + 1];
  us8 o;
  o[0] = f2bf(a.x); o[1] = f2bf(a.y); o[2] = f2bf(a.z); o[3] = f2bf(a.w);
  o[4] = f2bf(b.x); o[5] = f2bf(b.y); o[6] = f2bf(b.z); o[7] = f2bf(b.w);
  *(us8*)&XB[idx * 8] = o;
}

__global__ void sig16_kernel(const float* __restrict__ CT, const float* __restrict__ W1,
                             const float* __restrict__ B1, const float* __restrict__ W2,
                             float* __restrict__ SIG) {
  int i = blockIdx.x;            // 0..224
  int tid = threadIdx.x;         // 256
  float c0 = CT[i * 2 + 0], c1 = CT[i * 2 + 1];
  float a[16];
  #pragma unroll
  for (int hh = 0; hh < 16; ++hh) a[hh] = 0.f;
  #pragma unroll
  for (int jj = 0; jj < 2; ++jj) {
    int j = tid + jj * 256;
    float h = fmaxf(c0 * W1[j * 2 + 0] + c1 * W1[j * 2 + 1] + B1[j], 0.f);
    #pragma unroll
    for (int hh = 0; hh < 16; ++hh) a[hh] += h * W2[hh * 512 + j];
  }
  __shared__ float red[4][16];
  #pragma unroll
  for (int hh = 0; hh < 16; ++hh) {
    float v = a[hh];
    for (int m = 1; m < 64; m <<= 1) v += __shfl_xor(v, m);
    if ((tid & 63) == 0) red[tid >> 6][hh] = v;
  }
  __syncthreads();
  if (tid < 16) {
    float v = red[0][tid] + red[1][tid] + red[2][tid] + red[3][tid];
    SIG[i * 16 + tid] = 16.f / (1.f + __expf(-v));
  }
}

__global__ void cmb_kernel(const float* __restrict__ SIG, const float* __restrict__ MASK,
                           const int* __restrict__ RPI, float* __restrict__ CMB) {
  int b = blockIdx.x;            // (w,h) = 256 blocks
  int w = b >> 4, h = b & 15;
  int tid = threadIdx.x;
  const float* mrow = &MASK[(size_t)w * 4096];
  float* crow = &CMB[(size_t)b * 4096];
  #pragma unroll
  for (int it = 0; it < 16; ++it) {
    int nm = it * 256 + tid;
    crow[nm] = SIG[RPI[nm] * 16 + h] + mrow[nm];
  }
}

// ============ 128x256 / BK=32 / 8-wave / triple-buffer pipeline ============
// (round-9 verified; see notes there)

#define GEMM32_KLOOP()                                                     \
  _Pragma("unroll")                                                        \
  for (int t = 0; t < 16; ++t) {                                           \
    const int Sb = (t % 3) * 12288;                                        \
    _Pragma("unroll")                                                      \
    for (int m = 0; m < 4; ++m)                                            \
      af[m] = *(const bf16x8*)&S[Sb + (wm * 64 + m * 16 + fr) * 32 + fsw]; \
    _Pragma("unroll")                                                      \
    for (int n = 0; n < 2; ++n)                                            \
      bf[n] = *(const bf16x8*)&S[Sb + 4096 + (wn * 64 + n * 16 + fr) * 32 + fsw]; \
    if (t + 2 <= 15) stageB(t + 2);                                        \
    FENCE(); __builtin_amdgcn_s_barrier(); FENCE();                        \
    WAITL0(); __builtin_amdgcn_sched_barrier(0);                           \
    __builtin_amdgcn_s_setprio(1);                                         \
    _Pragma("unroll")                                                      \
    for (int m = 0; m < 4; ++m)                                            \
      _Pragma("unroll")                                                    \
      for (int n = 0; n < 2; ++n)                                          \
        acc[m][n] = mfma16(af[m], bf[n], acc[m][n]);                       \
    __builtin_amdgcn_s_setprio(0);                                         \
    FENCE(); __builtin_amdgcn_s_barrier(); FENCE();                        \
    _Pragma("unroll")                                                      \
    for (int n = 0; n < 2; ++n)                                            \
      bf[n] = *(const bf16x8*)&S[Sb + 4096 + (wn * 64 + (n + 2) * 16 + fr) * 32 + fsw]; \
    if (t + 3 <= 15) stageA(t + 3);                                        \
    if (t <= 12) { WAITV4(); }                                             \
    else if (t == 13) { WAITV3(); }                                        \
    else if (t == 14) { WAITV0(); }                                        \
    FENCE(); __builtin_amdgcn_s_barrier(); FENCE();                        \
    WAITL0(); __builtin_amdgcn_sched_barrier(0);                           \
    __builtin_amdgcn_s_setprio(1);                                         \
    _Pragma("unroll")                                                      \
    for (int m = 0; m < 4; ++m)                                            \
      _Pragma("unroll")                                                    \
      for (int n = 0; n < 2; ++n)                                          \
        acc[m][n + 2] = mfma16(af[m], bf[n], acc[m][n + 2]);               \
    __builtin_amdgcn_s_setprio(0);                                         \
    FENCE(); __builtin_amdgcn_s_barrier(); FENCE();                        \
  }

// ---------------- qkv GEMM: XB bf16 [131072,512] @ WQB^T -> bf16 [131072,1536] ----

__global__ __launch_bounds__(512, 4) void qkv_g32(
    const u16* __restrict__ XB, const u16* __restrict__ WB,
    const float* __restrict__ QB, const float* __restrict__ VB,
    u16* __restrict__ QKV) {
  __shared__ u16 S[36864];  // 3 x (A 4096 + B 8192) u16 = 73728 B
  const int tid = threadIdx.x, lane = tid & 63, w = tid >> 6;
  int bid = blockIdx.x;                           // 6144 = 1024m x 6n
  int swz = (bid & 7) * 768 + (bid >> 3);         // bijective XCD swizzle
  const int mt = swz / 6, nt = swz - mt * 6;
  const long m0 = (long)mt * 128, n0 = (long)nt * 256;
  const int wm = w >> 2, wn = w & 3;              // 2M x 4N waves; wave tile 64x64
  const int fr = lane & 15, lg = lane >> 4;
  const int fsw = (lg ^ ((fr >> 1) & 3)) << 3;    // swizzled chunk (u16 units)
  const f32x4 zf = {0.f, 0.f, 0.f, 0.f};

  f32x4 acc[4][4];
  #pragma unroll
  for (int mi = 0; mi < 4; ++mi)
    #pragma unroll
    for (int ni = 0; ni < 4; ++ni) acc[mi][ni] = zf;

  const int arow = tid >> 2;
  const int asc = (tid & 3) ^ ((arow >> 1) & 3);
  const u16* aSrc = &XB[(size_t)(m0 + arow) * 512 + asc * 8];
  const u16* bSrc0 = &WB[(size_t)(n0 + arow) * 512 + asc * 8];          // rows 0-127
  const u16* bSrc1 = &WB[(size_t)(n0 + 128 + arow) * 512 + asc * 8];    // rows 128-255

  auto stageA = [&](int kt) {
    gl_lds16(aSrc + kt * 32, &S[(kt % 3) * 12288 + w * 512]);
  };
  auto stageB = [&](int kt) {
    gl_lds16(bSrc0 + kt * 32, &S[(kt % 3) * 12288 + 4096 + w * 512]);
    gl_lds16(bSrc1 + kt * 32, &S[(kt % 3) * 12288 + 8192 + w * 512]);
  };

  bf16x8 af[4], bf[2];

  stageA(0); stageB(0); stageA(1); stageB(1); stageA(2);
  WAITV4();
  FENCE(); __builtin_amdgcn_s_barrier(); FENCE();

  GEMM32_KLOOP()

  // LDS-staged epilogue: per-wave [64][72] bf16 tile, then full-line us8 stores.
  u16* eb = &S[w * 4608];   // 64*72 u16 = 9216 B per wave; 8 waves = 73728 B
  #pragma unroll
  for (int ni = 0; ni < 4; ++ni) {
    const long c = n0 + wn * 64 + ni * 16 + fr;
    float bias = (c < 512) ? QB[c] : (c < 1024 ? 0.f : VB[c - 1024]);
    #pragma unroll
    for (int mi = 0; mi < 4; ++mi)
      #pragma unroll
      for (int r = 0; r < 4; ++r)
        eb[(mi * 16 + lg * 4 + r) * 72 + ni * 16 + fr] = f2bf(acc[mi][ni][r] + bias);
  }
  WAITL0();
  #pragma unroll
  for (int i = 0; i < 8; ++i) {
    int row = i * 8 + (lane >> 3);
    int c16 = lane & 7;
    us8 v = *(const us8*)&eb[row * 72 + c16 * 8];
    *(us8*)&QKV[(size_t)(m0 + wm * 64 + row) * 1536 + n0 + wn * 64 + c16 * 8] = v;
  }
}

// ---------------- proj GEMM: QKV q-cols bf16 [131072,512](lda=1536) @ WPB^T + b -> f32 ----

__global__ __launch_bounds__(512, 4) void proj_g32(
    const u16* __restrict__ A, const u16* __restrict__ WB,
    const float* __restrict__ PB, float* __restrict__ OUT) {
  __shared__ u16 S[36864];
  const int tid = threadIdx.x, lane = tid & 63, w = tid >> 6;
  int bid = blockIdx.x;                           // 2048 = 1024m x 2n
  int swz = (bid & 7) * 256 + (bid >> 3);
  const int mt = swz >> 1, nt = swz & 1;
  const long m0 = (long)mt * 128, n0 = (long)nt * 256;
  const int wm = w >> 2, wn = w & 3;
  const int fr = lane & 15, lg = lane >> 4;
  const int fsw = (lg ^ ((fr >> 1) & 3)) << 3;
  const f32x4 zf = {0.f, 0.f, 0.f, 0.f};

  f32x4 acc[4][4];
  #pragma unroll
  for (int mi = 0; mi < 4; ++mi)
    #pragma unroll
    for (int ni = 0; ni < 4; ++ni) acc[mi][ni] = zf;

  const int arow = tid >> 2;
  const int asc = (tid & 3) ^ ((arow >> 1) & 3);
  const u16* aSrc = &A[(size_t)(m0 + arow) * 1536 + asc * 8];           // lda 1536
  const u16* bSrc0 = &WB[(size_t)(n0 + arow) * 512 + asc * 8];
  const u16* bSrc1 = &WB[(size_t)(n0 + 128 + arow) * 512 + asc * 8];

  auto stageA = [&](int kt) {
    gl_lds16(aSrc + kt * 32, &S[(kt % 3) * 12288 + w * 512]);
  };
  auto stageB = [&](int kt) {
    gl_lds16(bSrc0 + kt * 32, &S[(kt % 3) * 12288 + 4096 + w * 512]);
    gl_lds16(bSrc1 + kt * 32, &S[(kt % 3) * 12288 + 8192 + w * 512]);
  };

  bf16x8 af[4], bf[2];

  stageA(0); stageB(0); stageA(1); stageB(1); stageA(2);
  WAITV4();
  FENCE(); __builtin_amdgcn_s_barrier(); FENCE();

  GEMM32_KLOOP()

  #pragma unroll
  for (int ni = 0; ni < 4; ++ni) {
    const long c = n0 + wn * 64 + ni * 16 + fr;
    float bias = PB[c];
    #pragma unroll
    for (int mi = 0; mi < 4; ++mi)
      #pragma unroll
      for (int r = 0; r < 4; ++r) {
        long row = m0 + wm * 64 + mi * 16 + lg * 4 + r;
        OUT[row * 512 + c] = acc[mi][ni][r] + bias;
      }
  }
}

// ---------------- qkv GEMM fallback (small ws): reg-staged A, 128x128 ----------------

__global__ __launch_bounds__(256, 2) void qkv_gemm_rs(
    const float* __restrict__ X, const u16* __restrict__ WB,
    const float* __restrict__ QB, const float* __restrict__ VB,
    u16* __restrict__ QKV) {
  __shared__ u16 As[128 * 64];
  __shared__ u16 Bs[128 * 64];
  const int tid = threadIdx.x, lane = tid & 63, w = tid >> 6;
  int bid = blockIdx.x;
  int swz = (bid & 7) * 1536 + (bid >> 3);
  const int mt = swz / 12, nt = swz - mt * 12;
  const long m0 = (long)mt * 128, n0 = (long)nt * 128;
  const int wm = w >> 1, wn = w & 1;
  const f32x4 zf = {0.f, 0.f, 0.f, 0.f};

  f32x4 acc[4][4];
  #pragma unroll
  for (int mi = 0; mi < 4; ++mi)
    #pragma unroll
    for (int ni = 0; ni < 4; ++ni) acc[mi][ni] = zf;

  const int fr = lane & 15;
  const int fsw = ((lane >> 4) ^ (lane & 7)) * 8;
  const u16* Ap = &As[(wm * 64 + fr) * 64 + fsw];
  const u16* Bp = &Bs[(wn * 64 + fr) * 64 + fsw];

  for (int t = 0; t < 8; ++t) {
    float4 av[8];
    #pragma unroll
    for (int i = 0; i < 8; ++i) {
      int ch = tid + (i << 8);
      int row = ch >> 4, kc = ch & 15;
      av[i] = *(const float4*)&X[(m0 + row) * 512 + t * 64 + kc * 4];
    }
    #pragma unroll
    for (int i = 0; i < 4; ++i) {
      int ch = ((w << 2) + i) * 64 + lane;
      int row = ch >> 3, kc = (ch & 7) ^ (row & 7);
      gl_lds16(&WB[(n0 + row) * 512 + t * 64 + kc * 8], &Bs[((w << 2) + i) * 512]);
    }
    #pragma unroll
    for (int i = 0; i < 8; ++i) {
      int ch = tid + (i << 8);
      int row = ch >> 4, kc = ch & 15;
      int kcs = kc ^ ((row & 7) << 1);
      us4 u; u.x = f2bf(av[i].x); u.y = f2bf(av[i].y); u.z = f2bf(av[i].z); u.w = f2bf(av[i].w);
      *(us4*)&As[row * 64 + kcs * 4] = u;
    }
    __syncthreads();
    #pragma unroll
    for (int ks = 0; ks < 2; ++ks) {
      bf16x8 af[4], bfr[4];
      #pragma unroll
      for (int mi = 0; mi < 4; ++mi) af[mi] = ldswz(Ap + mi * 1024, ks);
      #pragma unroll
      for (int ni = 0; ni < 4; ++ni) bfr[ni] = ldswz(Bp + ni * 1024, ks);
      #pragma unroll
      for (int mi = 0; mi < 4; ++mi)
        #pragma unroll
        for (int ni = 0; ni < 4; ++ni)
          acc[mi][ni] = mfma16(af[mi], bfr[ni], acc[mi][ni]);
    }
    __syncthreads();
  }

  #pragma unroll
  for (int ni = 0; ni < 4; ++ni) {
    const long c = n0 + wn * 64 + ni * 16 + (lane & 15);
    float bias = (c < 512) ? QB[c] : (c < 1024 ? 0.f : VB[c - 1024]);
    #pragma unroll
    for (int mi = 0; mi < 4; ++mi)
      #pragma unroll
      for (int r = 0; r < 4; ++r) {
        long row = m0 + wm * 64 + mi * 16 + (lane >> 4) * 4 + r;
        QKV[row * 1536 + c] = f2bf(acc[mi][ni][r] + bias);
      }
  }
}

// ---------------- attention: one (window, head) per wave, barrier-free ----------------
// Block = 4 waves = 4 heads of one window. Q/K: direct register fragments,
// row-norm via shfl_xor(16/32) (row's 32 cols live in lanes {fr, fr+16, fr+32, fr+48}).
// Bias+mask preloaded as MFMA C-input. Wave-private LDS: ps[64][68] + vt[32][68]
// (stride 68 u16 -> 2-way banking = free). No __syncthreads anywhere.

__global__ __launch_bounds__(256, 3) void attn_wh(
    u16* __restrict__ QKV, const float* __restrict__ CMB, const float* __restrict__ LS) {
  __shared__ u16 smu[26112];     // 4 waves x (4352 + 2176) u16 = 52224 B
  const int tid = threadIdx.x, lane = tid & 63, w = tid >> 6;
  const int b = blockIdx.x;
  const int win = b >> 2;        // 0..2047
  const int h = (b & 3) * 4 + w; // head 0..15
  const int wi = win & 15;
  const size_t base = (size_t)win * 64 * 1536;
  const int fr = lane & 15, lg = lane >> 4;
  u16* ps = &smu[w * 6528];      // [64][68]
  u16* vt = ps + 4352;           // [32][68]  (V^T: [d][key])
  const float scale = __expf(fminf(LS[h], 4.6051702f));
  const float* cp = &CMB[((size_t)(wi * 16 + h)) << 12];
  const f32x4 zf = {0.f, 0.f, 0.f, 0.f};

  // V rows -> registers (issue early; consumed after QK^T)
  us8 vrow[4];
  #pragma unroll
  for (int c = 0; c < 4; ++c)
    vrow[c] = *(const us8*)&QKV[base + (size_t)lane * 1536 + 1024 + h * 32 + c * 8];

  // acc = bias + mask  (C-input to QK^T: the add is free)
  f32x4 acc[4][4];
  #pragma unroll
  for (int m = 0; m < 4; ++m)
    #pragma unroll
    for (int n = 0; n < 4; ++n)
      #pragma unroll
      for (int r = 0; r < 4; ++r)
        acc[m][n][r] = cp[(m * 16 + lg * 4 + r) * 64 + n * 16 + fr];

  // Q,K: load own fragment, normalize in f32, convert to bf16 frags
  bf16x8 af[4], bk[4];
  #pragma unroll
  for (int m = 0; m < 4; ++m) {
    us8 qv = *(const us8*)&QKV[base + (size_t)(m * 16 + fr) * 1536 + h * 32 + lg * 8];
    float qf[8]; float ss = 0.f;
    #pragma unroll
    for (int j = 0; j < 8; ++j) { qf[j] = bf2f(qv[j]); ss += qf[j] * qf[j]; }
    ss += __shfl_xor(ss, 16); ss += __shfl_xor(ss, 32);
    float rn = scale / fmaxf(sqrtf(ss), 1e-12f);
    union { us8 u; bf16x8 b; } cv;
    #pragma unroll
    for (int j = 0; j < 8; ++j) cv.u[j] = f2bf(qf[j] * rn);
    af[m] = cv.b;
  }
  #pragma unroll
  for (int m = 0; m < 4; ++m) {
    us8 kv = *(const us8*)&QKV[base + (size_t)(m * 16 + fr) * 1536 + 512 + h * 32 + lg * 8];
    float kf[8]; float ss = 0.f;
    #pragma unroll
    for (int j = 0; j < 8; ++j) { kf[j] = bf2f(kv[j]); ss += kf[j] * kf[j]; }
    ss += __shfl_xor(ss, 16); ss += __shfl_xor(ss, 32);
    float rn = 1.f / fmaxf(sqrtf(ss), 1e-12f);
    union { us8 u; bf16x8 b; } cv;
    #pragma unroll
    for (int j = 0; j < 8; ++j) cv.u[j] = f2bf(kf[j] * rn);
    bk[m] = cv.b;
  }

  // QK^T (16 MFMA): S[m*16+lg*4+r][n*16+fr] = qn.kn*scale + bias
  #pragma unroll
  for (int m = 0; m < 4; ++m)
    #pragma unroll
    for (int n = 0; n < 4; ++n)
      acc[m][n] = mfma16(af[m], bk[n], acc[m][n]);

  // V^T into wave-private LDS: vt[d][key], lane = key
  #pragma unroll
  for (int c = 0; c < 4; ++c)
    #pragma unroll
    for (int j = 0; j < 8; ++j)
      vt[(c * 8 + j) * 68 + lane] = vrow[c][j];

  // softmax per row (16 rows/lane), write P to ps
  #pragma unroll
  for (int m = 0; m < 4; ++m)
    #pragma unroll
    for (int r = 0; r < 4; ++r) {
      float pv[4];
      float mx = -3.0e38f;
      #pragma unroll
      for (int n = 0; n < 4; ++n) { pv[n] = acc[m][n][r]; mx = fmaxf(mx, pv[n]); }
      mx = fmaxf(mx, __shfl_xor(mx, 1));
      mx = fmaxf(mx, __shfl_xor(mx, 2));
      mx = fmaxf(mx, __shfl_xor(mx, 4));
      mx = fmaxf(mx, __shfl_xor(mx, 8));
      float sum = 0.f;
      #pragma unroll
      for (int n = 0; n < 4; ++n) { pv[n] = __expf(pv[n] - mx); sum += pv[n]; }
      sum += __shfl_xor(sum, 1); sum += __shfl_xor(sum, 2);
      sum += __shfl_xor(sum, 4); sum += __shfl_xor(sum, 8);
      float inv = 1.f / sum;
      #pragma unroll
      for (int n = 0; n < 4; ++n)
        ps[(m * 16 + lg * 4 + r) * 68 + n * 16 + fr] = f2bf(pv[n] * inv);
    }

  // all wave-local LDS writes visible before reads (same wave, no barrier needed)
  WAITL0(); __builtin_amdgcn_sched_barrier(0);

  // PV (16 MFMA): O[64x32] = P @ V
  f32x4 o[4][2];
  #pragma unroll
  for (int m = 0; m < 4; ++m) { o[m][0] = zf; o[m][1] = zf; }
  #pragma unroll
  for (int m = 0; m < 4; ++m)
    #pragma unroll
    for (int ks = 0; ks < 2; ++ks) {
      bf16x8 ap = *(const bf16x8*)&ps[(m * 16 + fr) * 68 + ks * 32 + lg * 8];
      #pragma unroll
      for (int n2 = 0; n2 < 2; ++n2) {
        bf16x8 bv = *(const bf16x8*)&vt[(n2 * 16 + fr) * 68 + ks * 32 + lg * 8];
        o[m][n2] = mfma16(ap, bv, o[m][n2]);
      }
    }

  // store attn-out over the q-region cols of this head
  #pragma unroll
  for (int m = 0; m < 4; ++m)
    #pragma unroll
    for (int n2 = 0; n2 < 2; ++n2)
      #pragma unroll
      for (int r = 0; r < 4; ++r)
        QKV[base + (size_t)(m * 16 + lg * 4 + r) * 1536 + h * 32 + n2 * 16 + fr] =
            f2bf(o[m][n2][r]);
}

// ---------------- launch ----------------

extern "C" void kernel_launch(void* const* d_in, const int* in_sizes, int n_in,
                              void* d_out, int out_size, void* d_ws, size_t ws_size,
                              hipStream_t stream) {
  const float* X    = (const float*)d_in[0];
  const float* MASK = (const float*)d_in[1];
  const float* QW   = (const float*)d_in[2];
  const float* QB   = (const float*)d_in[3];
  const float* VB   = (const float*)d_in[4];
  const float* LS   = (const float*)d_in[5];
  const float* CW1  = (const float*)d_in[6];
  const float* CB1  = (const float*)d_in[7];
  const float* CW2  = (const float*)d_in[8];
  const float* PW   = (const float*)d_in[9];
  const float* PB   = (const float*)d_in[10];
  const float* CT   = (const float*)d_in[11];
  const int*   RPI  = (const int*)d_in[12];
  float* OUT = (float*)d_out;

  char* ws = (char*)d_ws;
  const bool big = ws_size >= 543178752ull;
  u16* QKV = (u16*)ws;                                    // 402,653,184 B
  u16* XB  = (u16*)(ws + 402653184ull);                   // 134,217,728 B (big only)
  size_t off = big ? 536870912ull : 402653184ull;
  float* CMB = (float*)(ws + off);  off += 4194304ull;    // 4 MB
  float* SIG = (float*)(ws + off);  off += 16384ull;
  u16*   WQB = (u16*)(ws + off);    off += 1572864ull;
  u16*   WPB = (u16*)(ws + off);

  conv_w_kernel<<<1024, 256, 0, stream>>>(QW, PW, WQB, WPB);
  sig16_kernel<<<225, 256, 0, stream>>>(CT, CW1, CB1, CW2, SIG);
  cmb_kernel<<<256, 256, 0, stream>>>(SIG, MASK, RPI, CMB);
  if (big) {
    xconv_kernel<<<32768, 256, 0, stream>>>(X, XB);
    qkv_g32<<<6144, 512, 0, stream>>>(XB, WQB, QB, VB, QKV);
  } else {
    qkv_gemm_rs<<<12288, 256, 0, stream>>>(X, WQB, QB, VB, QKV);
  }
  attn_wh<<<8192, 256, 0, stream>>>(QKV, CMB, LS);
  proj_g32<<<2048, 512, 0, stream>>>(QKV, WPB, PB, OUT);
}